// Round 1
// baseline (342.429 us; speedup 1.0000x reference)
//
#include <hip/hip_runtime.h>
#include <hip/hip_bf16.h>

typedef float f32x4_t __attribute__((ext_vector_type(4)));
typedef __bf16 bf16x8_t __attribute__((ext_vector_type(8)));

__device__ __forceinline__ float bf2f(unsigned short u){
  union { float f; unsigned int i; } x; x.i = ((unsigned int)u) << 16; return x.f;
}
__device__ __forceinline__ unsigned short f2bf(float f){
  unsigned int x = __float_as_uint(f);
  unsigned int r = (x + 0x7fffu + ((x >> 16) & 1u)) >> 16;
  return (unsigned short)r;
}

// ---------------- K0: pack weights (Wq|Wk|Wv|Ws) -> wcatT bf16 [1024][512], biases -> bcat f32[1024]
__global__ void pack_weights(const float* __restrict__ Wq, const float* __restrict__ Wk,
                             const float* __restrict__ Wv, const float* __restrict__ Ws,
                             const float* __restrict__ bq, const float* __restrict__ bk,
                             const float* __restrict__ bv, const float* __restrict__ bs,
                             unsigned short* __restrict__ wcatT, float* __restrict__ bcat){
  int idx = blockIdx.x * 256 + threadIdx.x;
  if (idx < 1024 * 512){
    int c = idx >> 9, k = idx & 511;
    int sel = c >> 8, cc = c & 255;
    const float* W = (sel == 0) ? Wq : (sel == 1) ? Wk : (sel == 2) ? Wv : Ws;
    wcatT[idx] = f2bf(W[k * 256 + cc]);
  }
  if (idx < 1024){
    int sel = idx >> 8, cc = idx & 255;
    const float* B = (sel == 0) ? bq : (sel == 1) ? bk : (sel == 2) ? bv : bs;
    bcat[idx] = B[cc];
  }
}

// ---------------- K1: x fp32 -> bf16
__global__ void convert_x(const float* __restrict__ x, unsigned short* __restrict__ xbf, int n4){
  int i = blockIdx.x * 256 + threadIdx.x;
  if (i < n4){
    float4 v = reinterpret_cast<const float4*>(x)[i];
    ushort4 o;
    o.x = f2bf(v.x); o.y = f2bf(v.y); o.z = f2bf(v.z); o.w = f2bf(v.w);
    reinterpret_cast<ushort4*>(xbf)[i] = o;
  }
}

// ---------------- K3: qkvs[n][1024] = xbf[n][512] @ wcatT^T + bcat  (bf16 MFMA, 64x64 tile)
__global__ __launch_bounds__(256) void gemm_qkvs(const unsigned short* __restrict__ xbf,
                                                 const unsigned short* __restrict__ wcatT,
                                                 const float* __restrict__ bcat,
                                                 unsigned short* __restrict__ qkvs, int n_nodes){
  __shared__ __align__(16) unsigned short As[64 * 40];
  __shared__ __align__(16) unsigned short Bs[64 * 40];
  const int tid = threadIdx.x;
  const int lane = tid & 63, wave = tid >> 6;
  const int wm = wave >> 1, wn = wave & 1;
  const int m0 = blockIdx.y * 64, n0 = blockIdx.x * 64;
  f32x4_t acc[2][2] = {};
  const int lrow = tid >> 2, lkc = (tid & 3) * 8;
  for (int k0 = 0; k0 < 512; k0 += 32){
    uint4 av = make_uint4(0, 0, 0, 0);
    if (m0 + lrow < n_nodes)
      av = *reinterpret_cast<const uint4*>(xbf + (size_t)(m0 + lrow) * 512 + k0 + lkc);
    *reinterpret_cast<uint4*>(&As[lrow * 40 + lkc]) = av;
    uint4 bv = *reinterpret_cast<const uint4*>(wcatT + (size_t)(n0 + lrow) * 512 + k0 + lkc);
    *reinterpret_cast<uint4*>(&Bs[lrow * 40 + lkc]) = bv;
    __syncthreads();
    int r = lane & 15, kg = (lane >> 4) * 8;
    bf16x8_t a0 = *reinterpret_cast<const bf16x8_t*>(&As[(wm * 32 + r) * 40 + kg]);
    bf16x8_t a1 = *reinterpret_cast<const bf16x8_t*>(&As[(wm * 32 + 16 + r) * 40 + kg]);
    bf16x8_t b0 = *reinterpret_cast<const bf16x8_t*>(&Bs[(wn * 32 + r) * 40 + kg]);
    bf16x8_t b1 = *reinterpret_cast<const bf16x8_t*>(&Bs[(wn * 32 + 16 + r) * 40 + kg]);
    acc[0][0] = __builtin_amdgcn_mfma_f32_16x16x32_bf16(a0, b0, acc[0][0], 0, 0, 0);
    acc[0][1] = __builtin_amdgcn_mfma_f32_16x16x32_bf16(a0, b1, acc[0][1], 0, 0, 0);
    acc[1][0] = __builtin_amdgcn_mfma_f32_16x16x32_bf16(a1, b0, acc[1][0], 0, 0, 0);
    acc[1][1] = __builtin_amdgcn_mfma_f32_16x16x32_bf16(a1, b1, acc[1][1], 0, 0, 0);
    __syncthreads();
  }
  int r = lane & 15, rg = (lane >> 4) * 4;
  for (int mi = 0; mi < 2; mi++){
    for (int j = 0; j < 4; j++){
      int grow = m0 + wm * 32 + mi * 16 + rg + j;
      if (grow < n_nodes){
        for (int ni = 0; ni < 2; ni++){
          int gcol = n0 + wn * 32 + ni * 16 + r;
          float v = acc[mi][ni][j] + bcat[gcol];
          qkvs[(size_t)grow * 1024 + gcol] = f2bf(v);
        }
      }
    }
  }
}

// ---------------- K4: degree histogram
__global__ void degree_hist(const int* __restrict__ ei, int* __restrict__ deg, int ne){
  int i = blockIdx.x * 256 + threadIdx.x;
  if (i < ne) atomicAdd(&deg[ei[ne + i]], 1);
}

// ---------------- K5: exclusive scan (single block, 1024 threads)
__global__ void scan_deg(const int* __restrict__ deg, int* __restrict__ rowstart, int n){
  __shared__ int sm[1024];
  __shared__ int carry;
  int tid = threadIdx.x;
  if (tid == 0) carry = 0;
  __syncthreads();
  for (int base = 0; base < n; base += 1024){
    int v = (base + tid < n) ? deg[base + tid] : 0;
    sm[tid] = v;
    __syncthreads();
    for (int off = 1; off < 1024; off <<= 1){
      int t = (tid >= off) ? sm[tid - off] : 0;
      __syncthreads();
      sm[tid] += t;
      __syncthreads();
    }
    if (base + tid < n) rowstart[base + tid] = carry + sm[tid] - v;
    __syncthreads();
    if (tid == 0) carry += sm[1023];
    __syncthreads();
  }
  if (tid == 0) rowstart[n] = carry;
}

// ---------------- K6: scatter edges into CSR
__global__ void scatter_edges(const int* __restrict__ ei, const int* __restrict__ rowstart,
                              int* __restrict__ cursor, int* __restrict__ csrsrc, int ne){
  int i = blockIdx.x * 256 + threadIdx.x;
  if (i < ne){
    int d = ei[ne + i];
    int pos = atomicAdd(&cursor[d], 1);
    csrsrc[rowstart[d] + pos] = ei[i];
  }
}

// ---------------- K7: per-dst online-softmax attention aggregation + residual + gelu -> h fp32
__global__ __launch_bounds__(256) void edge_attn(const unsigned short* __restrict__ qkvs,
                                                 const int* __restrict__ rowstart,
                                                 const int* __restrict__ csrsrc,
                                                 float* __restrict__ h, int n_nodes){
  int wave = threadIdx.x >> 6, lane = threadIdx.x & 63;
  int node = blockIdx.x * 4 + wave;
  if (node >= n_nodes) return;
  const unsigned short* base = qkvs + (size_t)node * 1024;
  ushort4 qa = *reinterpret_cast<const ushort4*>(base + lane * 4);
  float q0 = bf2f(qa.x) * 0.0625f, q1 = bf2f(qa.y) * 0.0625f;
  float q2 = bf2f(qa.z) * 0.0625f, q3 = bf2f(qa.w) * 0.0625f;
  int rs = rowstart[node], re = rowstart[node + 1];
  float m = -INFINITY, den = 0.f;
  float a0 = 0.f, a1 = 0.f, a2 = 0.f, a3 = 0.f;
  for (int i = rs; i < re; i++){
    int src = csrsrc[i];
    const unsigned short* kb = qkvs + (size_t)src * 1024 + 256;
    ushort4 kv = *reinterpret_cast<const ushort4*>(kb + lane * 4);
    float s = q0 * bf2f(kv.x) + q1 * bf2f(kv.y) + q2 * bf2f(kv.z) + q3 * bf2f(kv.w);
    s += __shfl_xor(s, 32); s += __shfl_xor(s, 16); s += __shfl_xor(s, 8);
    s += __shfl_xor(s, 4);  s += __shfl_xor(s, 2);  s += __shfl_xor(s, 1);
    float mn = fmaxf(m, s);
    float scale = expf(m - mn);
    float e = expf(s - mn);
    den = den * scale + e;
    const unsigned short* vb = qkvs + (size_t)src * 1024 + 512;
    ushort4 vv = *reinterpret_cast<const ushort4*>(vb + lane * 4);
    a0 = a0 * scale + e * bf2f(vv.x);
    a1 = a1 * scale + e * bf2f(vv.y);
    a2 = a2 * scale + e * bf2f(vv.z);
    a3 = a3 * scale + e * bf2f(vv.w);
    m = mn;
  }
  float inv = (den > 0.f) ? 1.0f / den : 0.f;
  ushort4 sl = *reinterpret_cast<const ushort4*>(base + 768 + lane * 4);
  float h0 = a0 * inv + bf2f(sl.x);
  float h1 = a1 * inv + bf2f(sl.y);
  float h2 = a2 * inv + bf2f(sl.z);
  float h3 = a3 * inv + bf2f(sl.w);
  const float inv_sqrt2 = 0.70710678118654752f;
  h0 = 0.5f * h0 * (1.0f + erff(h0 * inv_sqrt2));
  h1 = 0.5f * h1 * (1.0f + erff(h1 * inv_sqrt2));
  h2 = 0.5f * h2 * (1.0f + erff(h2 * inv_sqrt2));
  h3 = 0.5f * h3 * (1.0f + erff(h3 * inv_sqrt2));
  float4 out = make_float4(h0, h1, h2, h3);
  *reinterpret_cast<float4*>(h + (size_t)node * 256 + lane * 4) = out;
}

// ---------------- K8: s2[n][2] = tanh(h@Wa1 + ba1)@Wa2 + ba2  (fp32 tiled)
__global__ __launch_bounds__(256) void mlp_scores(const float* __restrict__ h,
                                                  const float* __restrict__ Wa1, const float* __restrict__ ba1,
                                                  const float* __restrict__ Wa2, const float* __restrict__ ba2,
                                                  float* __restrict__ s2, int n_nodes){
  __shared__ float hs[64 * 33];
  __shared__ float ws[32 * 65];
  int tid = threadIdx.x;
  int tx = tid & 15, ty = tid >> 4;
  int n0 = blockIdx.x * 64;
  float s2a[4][2] = {};
  for (int cp = 0; cp < 4; cp++){
    int c0 = cp * 64;
    float acc[4][4] = {};
    for (int k0 = 0; k0 < 256; k0 += 32){
      {
        int row = tid >> 2, kc = (tid & 3) * 8;
        float4 v0 = make_float4(0, 0, 0, 0), v1 = make_float4(0, 0, 0, 0);
        if (n0 + row < n_nodes){
          v0 = *reinterpret_cast<const float4*>(h + (size_t)(n0 + row) * 256 + k0 + kc);
          v1 = *reinterpret_cast<const float4*>(h + (size_t)(n0 + row) * 256 + k0 + kc + 4);
        }
        hs[row * 33 + kc + 0] = v0.x; hs[row * 33 + kc + 1] = v0.y;
        hs[row * 33 + kc + 2] = v0.z; hs[row * 33 + kc + 3] = v0.w;
        hs[row * 33 + kc + 4] = v1.x; hs[row * 33 + kc + 5] = v1.y;
        hs[row * 33 + kc + 6] = v1.z; hs[row * 33 + kc + 7] = v1.w;
        int kk = tid >> 3, cc = (tid & 7) * 8;
        float4 w0 = *reinterpret_cast<const float4*>(Wa1 + (size_t)(k0 + kk) * 256 + c0 + cc);
        float4 w1 = *reinterpret_cast<const float4*>(Wa1 + (size_t)(k0 + kk) * 256 + c0 + cc + 4);
        ws[kk * 65 + cc + 0] = w0.x; ws[kk * 65 + cc + 1] = w0.y;
        ws[kk * 65 + cc + 2] = w0.z; ws[kk * 65 + cc + 3] = w0.w;
        ws[kk * 65 + cc + 4] = w1.x; ws[kk * 65 + cc + 5] = w1.y;
        ws[kk * 65 + cc + 6] = w1.z; ws[kk * 65 + cc + 7] = w1.w;
      }
      __syncthreads();
      for (int k = 0; k < 32; k++){
        float ar[4], br[4];
        #pragma unroll
        for (int i = 0; i < 4; i++) ar[i] = hs[(ty * 4 + i) * 33 + k];
        #pragma unroll
        for (int i = 0; i < 4; i++) br[i] = ws[k * 65 + tx * 4 + i];
        #pragma unroll
        for (int i = 0; i < 4; i++)
          #pragma unroll
          for (int j = 0; j < 4; j++) acc[i][j] += ar[i] * br[j];
      }
      __syncthreads();
    }
    #pragma unroll
    for (int j = 0; j < 4; j++){
      int col = c0 + tx * 4 + j;
      float w20 = Wa2[col * 2], w21 = Wa2[col * 2 + 1];
      float b1 = ba1[col];
      #pragma unroll
      for (int i = 0; i < 4; i++){
        float t = tanhf(acc[i][j] + b1);
        s2a[i][0] += t * w20;
        s2a[i][1] += t * w21;
      }
    }
  }
  for (int i = 0; i < 4; i++){
    for (int c = 0; c < 2; c++){
      float v = s2a[i][c];
      v += __shfl_xor(v, 1); v += __shfl_xor(v, 2);
      v += __shfl_xor(v, 4); v += __shfl_xor(v, 8);
      if (tx == 0){
        int node = n0 + ty * 4 + i;
        if (node < n_nodes) s2[node * 2 + c] = v + ba2[c];
      }
    }
  }
}

// ---------------- K9: column max + exp-sum over 20000 (single block)
__global__ void col_reduce(const float* __restrict__ s2, float* __restrict__ red, int n){
  __shared__ float sm[1024];
  __shared__ float mshare[2];
  int tid = threadIdx.x;
  float mx0 = -INFINITY, mx1 = -INFINITY;
  for (int i = tid; i < n; i += 1024){
    mx0 = fmaxf(mx0, s2[2 * i]);
    mx1 = fmaxf(mx1, s2[2 * i + 1]);
  }
  sm[tid] = mx0; __syncthreads();
  for (int off = 512; off > 0; off >>= 1){
    if (tid < off) sm[tid] = fmaxf(sm[tid], sm[tid + off]);
    __syncthreads();
  }
  if (tid == 0) mshare[0] = sm[0];
  __syncthreads();
  sm[tid] = mx1; __syncthreads();
  for (int off = 512; off > 0; off >>= 1){
    if (tid < off) sm[tid] = fmaxf(sm[tid], sm[tid + off]);
    __syncthreads();
  }
  if (tid == 0) mshare[1] = sm[0];
  __syncthreads();
  float m0 = mshare[0], m1 = mshare[1];
  float s0 = 0.f, s1 = 0.f;
  for (int i = tid; i < n; i += 1024){
    s0 += expf(s2[2 * i] - m0);
    s1 += expf(s2[2 * i + 1] - m1);
  }
  sm[tid] = s0; __syncthreads();
  for (int off = 512; off > 0; off >>= 1){
    if (tid < off) sm[tid] += sm[tid + off];
    __syncthreads();
  }
  float den0 = sm[0];
  __syncthreads();
  sm[tid] = s1; __syncthreads();
  for (int off = 512; off > 0; off >>= 1){
    if (tid < off) sm[tid] += sm[tid + off];
    __syncthreads();
  }
  if (tid == 0){
    red[0] = m0; red[1] = m1; red[2] = den0; red[3] = sm[0];
  }
}

// ---------------- K10: attn, A output, M partial accumulation
__global__ __launch_bounds__(256) void attn_M(const float* __restrict__ s2, const float* __restrict__ red,
                                              const float* __restrict__ h, const int* __restrict__ label,
                                              float* __restrict__ Mbuf, float* __restrict__ outA, int n){
  __shared__ float a0s[256], a1s[256];
  int tid = threadIdx.x;
  int n0 = blockIdx.x * 256;
  int node = n0 + tid;
  float m0 = red[0], m1 = red[1];
  float i0 = 1.f / red[2], i1 = 1.f / red[3];
  float a0 = 0.f, a1 = 0.f;
  if (node < n){
    a0 = expf(s2[2 * node] - m0) * i0;
    a1 = expf(s2[2 * node + 1] - m1) * i1;
    outA[node] = (label[0] == 0) ? a0 : a1;
  }
  a0s[tid] = a0; a1s[tid] = a1;
  __syncthreads();
  int d = tid;
  float M0 = 0.f, M1 = 0.f;
  int cnt = min(256, n - n0);
  for (int i = 0; i < cnt; i++){
    float hv = h[(size_t)(n0 + i) * 256 + d];
    M0 += a0s[i] * hv;
    M1 += a1s[i] * hv;
  }
  atomicAdd(&Mbuf[d], M0);
  atomicAdd(&Mbuf[256 + d], M1);
}

// ---------------- K11: logits + Y_prob
__global__ void final_k(const float* __restrict__ Mbuf, const float* __restrict__ Wc,
                        const float* __restrict__ bc, float* __restrict__ out){
  __shared__ float sm[256];
  __shared__ float l0s;
  int tid = threadIdx.x;
  float p0 = Mbuf[tid] * Wc[tid];
  float p1 = Mbuf[256 + tid] * Wc[256 + tid];
  sm[tid] = p0; __syncthreads();
  for (int off = 128; off > 0; off >>= 1){
    if (tid < off) sm[tid] += sm[tid + off];
    __syncthreads();
  }
  if (tid == 0) l0s = sm[0];
  __syncthreads();
  sm[tid] = p1; __syncthreads();
  for (int off = 128; off > 0; off >>= 1){
    if (tid < off) sm[tid] += sm[tid + off];
    __syncthreads();
  }
  if (tid == 0){
    float l0 = l0s + bc[0];
    float l1 = sm[0] + bc[1];
    out[0] = l0; out[1] = l1;
    float mx = fmaxf(l0, l1);
    float e0 = expf(l0 - mx), e1 = expf(l1 - mx);
    float inv = 1.f / (e0 + e1);
    out[2] = e0 * inv; out[3] = e1 * inv;
  }
}

extern "C" void kernel_launch(void* const* d_in, const int* in_sizes, int n_in,
                              void* d_out, int out_size, void* d_ws, size_t ws_size,
                              hipStream_t stream) {
  const float* x   = (const float*)d_in[0];
  const int*   ei  = (const int*)d_in[1];
  const int*   lab = (const int*)d_in[2];
  const float* Wq  = (const float*)d_in[3];
  const float* bq  = (const float*)d_in[4];
  const float* Wk  = (const float*)d_in[5];
  const float* bk  = (const float*)d_in[6];
  const float* Wv  = (const float*)d_in[7];
  const float* bv  = (const float*)d_in[8];
  const float* Ws  = (const float*)d_in[9];
  const float* bs  = (const float*)d_in[10];
  const float* Wa1 = (const float*)d_in[11];
  const float* ba1 = (const float*)d_in[12];
  const float* Wa2 = (const float*)d_in[13];
  const float* ba2 = (const float*)d_in[14];
  const float* Wc  = (const float*)d_in[15];
  const float* bc  = (const float*)d_in[16];
  float* out = (float*)d_out;

  const int n  = in_sizes[0] / 512;   // 20000
  const int ne = in_sizes[1] / 2;     // 320000

  char* ws = (char*)d_ws;
  size_t off = 0;
  auto take = [&](size_t bytes){ size_t r = off; off += (bytes + 255) & ~(size_t)255; return r; };
  unsigned short* xbf    = (unsigned short*)(ws + take((size_t)n * 512 * 2));
  unsigned short* wcatT  = (unsigned short*)(ws + take((size_t)1024 * 512 * 2));
  float*          bcat   = (float*)(ws + take(1024 * 4));
  unsigned short* qkvs   = (unsigned short*)(ws + take((size_t)n * 1024 * 2));
  float*          h      = (float*)(ws + take((size_t)n * 256 * 4));
  float*          s2     = (float*)(ws + take((size_t)n * 2 * 4));
  int*            deg    = (int*)(ws + take((size_t)n * 4));
  int*            cursor = (int*)(ws + take((size_t)n * 4));
  int*            rowst  = (int*)(ws + take((size_t)(n + 1) * 4));
  int*            csrsrc = (int*)(ws + take((size_t)ne * 4));
  float*          Mbuf   = (float*)(ws + take(512 * 4));
  float*          red    = (float*)(ws + take(4 * 4));

  // zero accumulators (ws is not re-poisoned between replays)
  hipMemsetAsync(deg, 0, (size_t)n * 4, stream);
  hipMemsetAsync(cursor, 0, (size_t)n * 4, stream);
  hipMemsetAsync(Mbuf, 0, 512 * 4, stream);

  pack_weights<<<(1024 * 512 + 255) / 256, 256, 0, stream>>>(Wq, Wk, Wv, Ws, bq, bk, bv, bs, wcatT, bcat);
  convert_x<<<(n * 512 / 4 + 255) / 256, 256, 0, stream>>>(x, xbf, n * 512 / 4);
  dim3 ggrid(16, (n + 63) / 64);
  gemm_qkvs<<<ggrid, 256, 0, stream>>>(xbf, wcatT, bcat, qkvs, n);
  degree_hist<<<(ne + 255) / 256, 256, 0, stream>>>(ei, deg, ne);
  scan_deg<<<1, 1024, 0, stream>>>(deg, rowst, n);
  scatter_edges<<<(ne + 255) / 256, 256, 0, stream>>>(ei, rowst, cursor, csrsrc, ne);
  edge_attn<<<(n + 3) / 4, 256, 0, stream>>>(qkvs, rowst, csrsrc, h, n);
  mlp_scores<<<(n + 63) / 64, 256, 0, stream>>>(h, Wa1, ba1, Wa2, ba2, s2, n);
  col_reduce<<<1, 1024, 0, stream>>>(s2, red, n);
  attn_M<<<(n + 255) / 256, 256, 0, stream>>>(s2, red, h, lab, Mbuf, out + 4, n);
  final_k<<<1, 256, 0, stream>>>(Mbuf, Wc, bc, out);
  (void)ws_size; (void)out_size; (void)n_in;
}

// Round 2
// 265.583 us; speedup vs baseline: 1.2893x; 1.2893x over previous
//
#include <hip/hip_runtime.h>
#include <hip/hip_bf16.h>

typedef float f32x4_t __attribute__((ext_vector_type(4)));
typedef __bf16 bf16x8_t __attribute__((ext_vector_type(8)));

__device__ __forceinline__ float bf2f(unsigned short u){
  union { float f; unsigned int i; } x; x.i = ((unsigned int)u) << 16; return x.f;
}
__device__ __forceinline__ unsigned short f2bf(float f){
  unsigned int x = __float_as_uint(f);
  unsigned int r = (x + 0x7fffu + ((x >> 16) & 1u)) >> 16;
  return (unsigned short)r;
}

// ---------------- K0: pack weights (Wq|Wk|Wv|Ws) -> wcatT bf16 [1024][512], biases -> bcat f32[1024]
__global__ void pack_weights(const float* __restrict__ Wq, const float* __restrict__ Wk,
                             const float* __restrict__ Wv, const float* __restrict__ Ws,
                             const float* __restrict__ bq, const float* __restrict__ bk,
                             const float* __restrict__ bv, const float* __restrict__ bs,
                             unsigned short* __restrict__ wcatT, float* __restrict__ bcat){
  int idx = blockIdx.x * 256 + threadIdx.x;
  if (idx < 1024 * 512){
    int c = idx >> 9, k = idx & 511;
    int sel = c >> 8, cc = c & 255;
    const float* W = (sel == 0) ? Wq : (sel == 1) ? Wk : (sel == 2) ? Wv : Ws;
    wcatT[idx] = f2bf(W[k * 256 + cc]);
  }
  if (idx < 1024){
    int sel = idx >> 8, cc = idx & 255;
    const float* B = (sel == 0) ? bq : (sel == 1) ? bk : (sel == 2) ? bv : bs;
    bcat[idx] = B[cc];
  }
}

// ---------------- K0b: pack Wa1^T -> bf16 [256 cols][256 k]
__global__ void pack_wa1(const float* __restrict__ Wa1, unsigned short* __restrict__ wa1T){
  int idx = blockIdx.x * 256 + threadIdx.x;  // 65536
  int c = idx >> 8, k = idx & 255;
  wa1T[idx] = f2bf(Wa1[k * 256 + c]);
}

// ---------------- K1: x fp32 -> bf16
__global__ void convert_x(const float* __restrict__ x, unsigned short* __restrict__ xbf, int n4){
  int i = blockIdx.x * 256 + threadIdx.x;
  if (i < n4){
    float4 v = reinterpret_cast<const float4*>(x)[i];
    ushort4 o;
    o.x = f2bf(v.x); o.y = f2bf(v.y); o.z = f2bf(v.z); o.w = f2bf(v.w);
    reinterpret_cast<ushort4*>(xbf)[i] = o;
  }
}

// ---------------- K3: qkvs[n][1024] = xbf[n][512] @ wcatT^T + bcat  (bf16 MFMA, 64x64 tile)
__global__ __launch_bounds__(256) void gemm_qkvs(const unsigned short* __restrict__ xbf,
                                                 const unsigned short* __restrict__ wcatT,
                                                 const float* __restrict__ bcat,
                                                 unsigned short* __restrict__ qkvs, int n_nodes){
  __shared__ __align__(16) unsigned short As[64 * 40];
  __shared__ __align__(16) unsigned short Bs[64 * 40];
  const int tid = threadIdx.x;
  const int lane = tid & 63, wave = tid >> 6;
  const int wm = wave >> 1, wn = wave & 1;
  const int m0 = blockIdx.y * 64, n0 = blockIdx.x * 64;
  f32x4_t acc[2][2] = {};
  const int lrow = tid >> 2, lkc = (tid & 3) * 8;
  for (int k0 = 0; k0 < 512; k0 += 32){
    uint4 av = make_uint4(0, 0, 0, 0);
    if (m0 + lrow < n_nodes)
      av = *reinterpret_cast<const uint4*>(xbf + (size_t)(m0 + lrow) * 512 + k0 + lkc);
    *reinterpret_cast<uint4*>(&As[lrow * 40 + lkc]) = av;
    uint4 bv = *reinterpret_cast<const uint4*>(wcatT + (size_t)(n0 + lrow) * 512 + k0 + lkc);
    *reinterpret_cast<uint4*>(&Bs[lrow * 40 + lkc]) = bv;
    __syncthreads();
    int r = lane & 15, kg = (lane >> 4) * 8;
    bf16x8_t a0 = *reinterpret_cast<const bf16x8_t*>(&As[(wm * 32 + r) * 40 + kg]);
    bf16x8_t a1 = *reinterpret_cast<const bf16x8_t*>(&As[(wm * 32 + 16 + r) * 40 + kg]);
    bf16x8_t b0 = *reinterpret_cast<const bf16x8_t*>(&Bs[(wn * 32 + r) * 40 + kg]);
    bf16x8_t b1 = *reinterpret_cast<const bf16x8_t*>(&Bs[(wn * 32 + 16 + r) * 40 + kg]);
    acc[0][0] = __builtin_amdgcn_mfma_f32_16x16x32_bf16(a0, b0, acc[0][0], 0, 0, 0);
    acc[0][1] = __builtin_amdgcn_mfma_f32_16x16x32_bf16(a0, b1, acc[0][1], 0, 0, 0);
    acc[1][0] = __builtin_amdgcn_mfma_f32_16x16x32_bf16(a1, b0, acc[1][0], 0, 0, 0);
    acc[1][1] = __builtin_amdgcn_mfma_f32_16x16x32_bf16(a1, b1, acc[1][1], 0, 0, 0);
    __syncthreads();
  }
  int r = lane & 15, rg = (lane >> 4) * 4;
  for (int mi = 0; mi < 2; mi++){
    for (int j = 0; j < 4; j++){
      int grow = m0 + wm * 32 + mi * 16 + rg + j;
      if (grow < n_nodes){
        for (int ni = 0; ni < 2; ni++){
          int gcol = n0 + wn * 32 + ni * 16 + r;
          float v = acc[mi][ni][j] + bcat[gcol];
          qkvs[(size_t)grow * 1024 + gcol] = f2bf(v);
        }
      }
    }
  }
}

// ---------------- K4: degree histogram
__global__ void degree_hist(const int* __restrict__ ei, int* __restrict__ deg, int ne){
  int i = blockIdx.x * 256 + threadIdx.x;
  if (i < ne) atomicAdd(&deg[ei[ne + i]], 1);
}

// ---------------- K5: exclusive scan (single block, 1024 threads)
__global__ void scan_deg(const int* __restrict__ deg, int* __restrict__ rowstart, int n){
  __shared__ int sm[1024];
  __shared__ int carry;
  int tid = threadIdx.x;
  if (tid == 0) carry = 0;
  __syncthreads();
  for (int base = 0; base < n; base += 1024){
    int v = (base + tid < n) ? deg[base + tid] : 0;
    sm[tid] = v;
    __syncthreads();
    for (int off = 1; off < 1024; off <<= 1){
      int t = (tid >= off) ? sm[tid - off] : 0;
      __syncthreads();
      sm[tid] += t;
      __syncthreads();
    }
    if (base + tid < n) rowstart[base + tid] = carry + sm[tid] - v;
    __syncthreads();
    if (tid == 0) carry += sm[1023];
    __syncthreads();
  }
  if (tid == 0) rowstart[n] = carry;
}

// ---------------- K6: scatter edges into CSR
__global__ void scatter_edges(const int* __restrict__ ei, const int* __restrict__ rowstart,
                              int* __restrict__ cursor, int* __restrict__ csrsrc, int ne){
  int i = blockIdx.x * 256 + threadIdx.x;
  if (i < ne){
    int d = ei[ne + i];
    int pos = atomicAdd(&cursor[d], 1);
    csrsrc[rowstart[d] + pos] = ei[i];
  }
}

// ---------------- K7: per-dst online-softmax attention aggregation + residual + gelu -> h fp32 + hbf bf16
__global__ __launch_bounds__(256) void edge_attn(const unsigned short* __restrict__ qkvs,
                                                 const int* __restrict__ rowstart,
                                                 const int* __restrict__ csrsrc,
                                                 float* __restrict__ h,
                                                 unsigned short* __restrict__ hbf, int n_nodes){
  int wave = threadIdx.x >> 6, lane = threadIdx.x & 63;
  int node = blockIdx.x * 4 + wave;
  if (node >= n_nodes) return;
  const unsigned short* base = qkvs + (size_t)node * 1024;
  ushort4 qa = *reinterpret_cast<const ushort4*>(base + lane * 4);
  float q0 = bf2f(qa.x) * 0.0625f, q1 = bf2f(qa.y) * 0.0625f;
  float q2 = bf2f(qa.z) * 0.0625f, q3 = bf2f(qa.w) * 0.0625f;
  int rs = rowstart[node], re = rowstart[node + 1];
  float m = -INFINITY, den = 0.f;
  float a0 = 0.f, a1 = 0.f, a2 = 0.f, a3 = 0.f;
  for (int i = rs; i < re; i++){
    int src = csrsrc[i];
    const unsigned short* kb = qkvs + (size_t)src * 1024 + 256;
    ushort4 kv = *reinterpret_cast<const ushort4*>(kb + lane * 4);
    float s = q0 * bf2f(kv.x) + q1 * bf2f(kv.y) + q2 * bf2f(kv.z) + q3 * bf2f(kv.w);
    s += __shfl_xor(s, 32); s += __shfl_xor(s, 16); s += __shfl_xor(s, 8);
    s += __shfl_xor(s, 4);  s += __shfl_xor(s, 2);  s += __shfl_xor(s, 1);
    float mn = fmaxf(m, s);
    float scale = expf(m - mn);
    float e = expf(s - mn);
    den = den * scale + e;
    const unsigned short* vb = qkvs + (size_t)src * 1024 + 512;
    ushort4 vv = *reinterpret_cast<const ushort4*>(vb + lane * 4);
    a0 = a0 * scale + e * bf2f(vv.x);
    a1 = a1 * scale + e * bf2f(vv.y);
    a2 = a2 * scale + e * bf2f(vv.z);
    a3 = a3 * scale + e * bf2f(vv.w);
    m = mn;
  }
  float inv = (den > 0.f) ? 1.0f / den : 0.f;
  ushort4 sl = *reinterpret_cast<const ushort4*>(base + 768 + lane * 4);
  float h0 = a0 * inv + bf2f(sl.x);
  float h1 = a1 * inv + bf2f(sl.y);
  float h2 = a2 * inv + bf2f(sl.z);
  float h3 = a3 * inv + bf2f(sl.w);
  const float inv_sqrt2 = 0.70710678118654752f;
  h0 = 0.5f * h0 * (1.0f + erff(h0 * inv_sqrt2));
  h1 = 0.5f * h1 * (1.0f + erff(h1 * inv_sqrt2));
  h2 = 0.5f * h2 * (1.0f + erff(h2 * inv_sqrt2));
  h3 = 0.5f * h3 * (1.0f + erff(h3 * inv_sqrt2));
  *reinterpret_cast<float4*>(h + (size_t)node * 256 + lane * 4) = make_float4(h0, h1, h2, h3);
  ushort4 ho;
  ho.x = f2bf(h0); ho.y = f2bf(h1); ho.z = f2bf(h2); ho.w = f2bf(h3);
  *reinterpret_cast<ushort4*>(hbf + (size_t)node * 256 + lane * 4) = ho;
}

// ---------------- K8: s2[n][2] = tanh(hbf@Wa1 + ba1)@Wa2 + ba2  (bf16 MFMA, 64-row blocks)
__global__ __launch_bounds__(256) void mlp_mfma(const unsigned short* __restrict__ hbf,
                                                const unsigned short* __restrict__ wa1T,
                                                const float* __restrict__ ba1,
                                                const float* __restrict__ Wa2,
                                                const float* __restrict__ ba2,
                                                float* __restrict__ s2, int n_nodes){
  __shared__ __align__(16) unsigned short As[64 * 72];
  __shared__ float s2s[64][2];
  const int tid = threadIdx.x;
  const int lane = tid & 63, wave = tid >> 6;
  const int m0 = blockIdx.x * 64;
  const int c0 = wave * 64;          // each wave owns 64 output columns
  const int r = lane & 15, rg = (lane >> 4) * 4;
  if (tid < 128) s2s[tid >> 1][tid & 1] = 0.f;
  f32x4_t acc[4][4] = {};            // 64 rows x 64 cols per wave
  for (int k0 = 0; k0 < 256; k0 += 64){
    // stage A: 64 rows x 64 k, each thread writes 16 elems (two uint4)
    int arow = tid >> 2, akc = (tid & 3) * 16;
    uint4 a0v = make_uint4(0,0,0,0), a1v = make_uint4(0,0,0,0);
    if (m0 + arow < n_nodes){
      const unsigned short* src = hbf + (size_t)(m0 + arow) * 256 + k0 + akc;
      a0v = *reinterpret_cast<const uint4*>(src);
      a1v = *reinterpret_cast<const uint4*>(src + 8);
    }
    *reinterpret_cast<uint4*>(&As[arow * 72 + akc]) = a0v;
    *reinterpret_cast<uint4*>(&As[arow * 72 + akc + 8]) = a1v;
    __syncthreads();
    #pragma unroll
    for (int kk = 0; kk < 2; kk++){
      int kg = kk * 32 + (lane >> 4) * 8;
      bf16x8_t a[4], b[4];
      #pragma unroll
      for (int mi = 0; mi < 4; mi++)
        a[mi] = *reinterpret_cast<const bf16x8_t*>(&As[(mi * 16 + r) * 72 + kg]);
      #pragma unroll
      for (int ni = 0; ni < 4; ni++)
        b[ni] = *reinterpret_cast<const bf16x8_t*>(wa1T + (size_t)(c0 + ni * 16 + r) * 256 + k0 + kg);
      #pragma unroll
      for (int mi = 0; mi < 4; mi++)
        #pragma unroll
        for (int ni = 0; ni < 4; ni++)
          acc[mi][ni] = __builtin_amdgcn_mfma_f32_16x16x32_bf16(a[mi], b[ni], acc[mi][ni], 0, 0, 0);
    }
    __syncthreads();
  }
  // epilogue: t = tanh(acc + ba1), partial s2 = t @ Wa2, reduce over cols
  float w20[4], w21[4], b1c[4];
  #pragma unroll
  for (int ni = 0; ni < 4; ni++){
    int col = c0 + ni * 16 + r;
    w20[ni] = Wa2[col * 2]; w21[ni] = Wa2[col * 2 + 1]; b1c[ni] = ba1[col];
  }
  #pragma unroll
  for (int mi = 0; mi < 4; mi++){
    #pragma unroll
    for (int j = 0; j < 4; j++){
      float t0 = 0.f, t1 = 0.f;
      #pragma unroll
      for (int ni = 0; ni < 4; ni++){
        float t = tanhf(acc[mi][ni][j] + b1c[ni]);
        t0 += t * w20[ni]; t1 += t * w21[ni];
      }
      t0 += __shfl_xor(t0, 1); t0 += __shfl_xor(t0, 2);
      t0 += __shfl_xor(t0, 4); t0 += __shfl_xor(t0, 8);
      t1 += __shfl_xor(t1, 1); t1 += __shfl_xor(t1, 2);
      t1 += __shfl_xor(t1, 4); t1 += __shfl_xor(t1, 8);
      if (r == 0){
        int row = mi * 16 + rg + j;
        atomicAdd(&s2s[row][0], t0);
        atomicAdd(&s2s[row][1], t1);
      }
    }
  }
  __syncthreads();
  if (tid < 128){
    int row = tid >> 1, c = tid & 1;
    int node = m0 + row;
    if (node < n_nodes) s2[node * 2 + c] = s2s[row][c] + ba2[c];
  }
}

// ---------------- K9: column max + exp-sum over 20000 (single block)
__global__ void col_reduce(const float* __restrict__ s2, float* __restrict__ red, int n){
  __shared__ float sm[1024];
  __shared__ float mshare[2];
  int tid = threadIdx.x;
  float mx0 = -INFINITY, mx1 = -INFINITY;
  for (int i = tid; i < n; i += 1024){
    mx0 = fmaxf(mx0, s2[2 * i]);
    mx1 = fmaxf(mx1, s2[2 * i + 1]);
  }
  sm[tid] = mx0; __syncthreads();
  for (int off = 512; off > 0; off >>= 1){
    if (tid < off) sm[tid] = fmaxf(sm[tid], sm[tid + off]);
    __syncthreads();
  }
  if (tid == 0) mshare[0] = sm[0];
  __syncthreads();
  sm[tid] = mx1; __syncthreads();
  for (int off = 512; off > 0; off >>= 1){
    if (tid < off) sm[tid] = fmaxf(sm[tid], sm[tid + off]);
    __syncthreads();
  }
  if (tid == 0) mshare[1] = sm[0];
  __syncthreads();
  float m0 = mshare[0], m1 = mshare[1];
  float s0 = 0.f, s1 = 0.f;
  for (int i = tid; i < n; i += 1024){
    s0 += expf(s2[2 * i] - m0);
    s1 += expf(s2[2 * i + 1] - m1);
  }
  sm[tid] = s0; __syncthreads();
  for (int off = 512; off > 0; off >>= 1){
    if (tid < off) sm[tid] += sm[tid + off];
    __syncthreads();
  }
  float den0 = sm[0];
  __syncthreads();
  sm[tid] = s1; __syncthreads();
  for (int off = 512; off > 0; off >>= 1){
    if (tid < off) sm[tid] += sm[tid + off];
    __syncthreads();
  }
  if (tid == 0){
    red[0] = m0; red[1] = m1; red[2] = den0; red[3] = sm[0];
  }
}

// ---------------- K10: attn, A output, M partial accumulation
__global__ __launch_bounds__(256) void attn_M(const float* __restrict__ s2, const float* __restrict__ red,
                                              const float* __restrict__ h, const int* __restrict__ label,
                                              float* __restrict__ Mbuf, float* __restrict__ outA, int n){
  __shared__ float a0s[256], a1s[256];
  int tid = threadIdx.x;
  int n0 = blockIdx.x * 256;
  int node = n0 + tid;
  float m0 = red[0], m1 = red[1];
  float i0 = 1.f / red[2], i1 = 1.f / red[3];
  float a0 = 0.f, a1 = 0.f;
  if (node < n){
    a0 = expf(s2[2 * node] - m0) * i0;
    a1 = expf(s2[2 * node + 1] - m1) * i1;
    outA[node] = (label[0] == 0) ? a0 : a1;
  }
  a0s[tid] = a0; a1s[tid] = a1;
  __syncthreads();
  int d = tid;
  float M0 = 0.f, M1 = 0.f;
  int cnt = min(256, n - n0);
  for (int i = 0; i < cnt; i++){
    float hv = h[(size_t)(n0 + i) * 256 + d];
    M0 += a0s[i] * hv;
    M1 += a1s[i] * hv;
  }
  atomicAdd(&Mbuf[d], M0);
  atomicAdd(&Mbuf[256 + d], M1);
}

// ---------------- K11: logits + Y_prob
__global__ void final_k(const float* __restrict__ Mbuf, const float* __restrict__ Wc,
                        const float* __restrict__ bc, float* __restrict__ out){
  __shared__ float sm[256];
  __shared__ float l0s;
  int tid = threadIdx.x;
  float p0 = Mbuf[tid] * Wc[tid];
  float p1 = Mbuf[256 + tid] * Wc[256 + tid];
  sm[tid] = p0; __syncthreads();
  for (int off = 128; off > 0; off >>= 1){
    if (tid < off) sm[tid] += sm[tid + off];
    __syncthreads();
  }
  if (tid == 0) l0s = sm[0];
  __syncthreads();
  sm[tid] = p1; __syncthreads();
  for (int off = 128; off > 0; off >>= 1){
    if (tid < off) sm[tid] += sm[tid + off];
    __syncthreads();
  }
  if (tid == 0){
    float l0 = l0s + bc[0];
    float l1 = sm[0] + bc[1];
    out[0] = l0; out[1] = l1;
    float mx = fmaxf(l0, l1);
    float e0 = expf(l0 - mx), e1 = expf(l1 - mx);
    float inv = 1.f / (e0 + e1);
    out[2] = e0 * inv; out[3] = e1 * inv;
  }
}

extern "C" void kernel_launch(void* const* d_in, const int* in_sizes, int n_in,
                              void* d_out, int out_size, void* d_ws, size_t ws_size,
                              hipStream_t stream) {
  const float* x   = (const float*)d_in[0];
  const int*   ei  = (const int*)d_in[1];
  const int*   lab = (const int*)d_in[2];
  const float* Wq  = (const float*)d_in[3];
  const float* bq  = (const float*)d_in[4];
  const float* Wk  = (const float*)d_in[5];
  const float* bk  = (const float*)d_in[6];
  const float* Wv  = (const float*)d_in[7];
  const float* bv  = (const float*)d_in[8];
  const float* Ws  = (const float*)d_in[9];
  const float* bs  = (const float*)d_in[10];
  const float* Wa1 = (const float*)d_in[11];
  const float* ba1 = (const float*)d_in[12];
  const float* Wa2 = (const float*)d_in[13];
  const float* ba2 = (const float*)d_in[14];
  const float* Wc  = (const float*)d_in[15];
  const float* bc  = (const float*)d_in[16];
  float* out = (float*)d_out;

  const int n  = in_sizes[0] / 512;   // 20000
  const int ne = in_sizes[1] / 2;     // 320000

  char* ws = (char*)d_ws;
  size_t off = 0;
  auto take = [&](size_t bytes){ size_t r = off; off += (bytes + 255) & ~(size_t)255; return r; };
  unsigned short* xbf    = (unsigned short*)(ws + take((size_t)n * 512 * 2));
  unsigned short* wcatT  = (unsigned short*)(ws + take((size_t)1024 * 512 * 2));
  float*          bcat   = (float*)(ws + take(1024 * 4));
  unsigned short* qkvs   = (unsigned short*)(ws + take((size_t)n * 1024 * 2));
  float*          h      = (float*)(ws + take((size_t)n * 256 * 4));
  unsigned short* hbf    = (unsigned short*)(ws + take((size_t)n * 256 * 2));
  unsigned short* wa1T   = (unsigned short*)(ws + take((size_t)256 * 256 * 2));
  float*          s2     = (float*)(ws + take((size_t)n * 2 * 4));
  int*            deg    = (int*)(ws + take((size_t)n * 4));
  int*            cursor = (int*)(ws + take((size_t)n * 4));
  int*            rowst  = (int*)(ws + take((size_t)(n + 1) * 4));
  int*            csrsrc = (int*)(ws + take((size_t)ne * 4));
  float*          Mbuf   = (float*)(ws + take(512 * 4));
  float*          red    = (float*)(ws + take(4 * 4));

  // zero accumulators (ws is not re-poisoned between replays)
  hipMemsetAsync(deg, 0, (size_t)n * 4, stream);
  hipMemsetAsync(cursor, 0, (size_t)n * 4, stream);
  hipMemsetAsync(Mbuf, 0, 512 * 4, stream);

  pack_weights<<<(1024 * 512 + 255) / 256, 256, 0, stream>>>(Wq, Wk, Wv, Ws, bq, bk, bv, bs, wcatT, bcat);
  pack_wa1<<<256, 256, 0, stream>>>(Wa1, wa1T);
  convert_x<<<(n * 512 / 4 + 255) / 256, 256, 0, stream>>>(x, xbf, n * 512 / 4);
  dim3 ggrid(16, (n + 63) / 64);
  gemm_qkvs<<<ggrid, 256, 0, stream>>>(xbf, wcatT, bcat, qkvs, n);
  degree_hist<<<(ne + 255) / 256, 256, 0, stream>>>(ei, deg, ne);
  scan_deg<<<1, 1024, 0, stream>>>(deg, rowst, n);
  scatter_edges<<<(ne + 255) / 256, 256, 0, stream>>>(ei, rowst, cursor, csrsrc, ne);
  edge_attn<<<(n + 3) / 4, 256, 0, stream>>>(qkvs, rowst, csrsrc, h, hbf, n);
  mlp_mfma<<<(n + 63) / 64, 256, 0, stream>>>(hbf, wa1T, ba1, Wa2, ba2, s2, n);
  col_reduce<<<1, 1024, 0, stream>>>(s2, red, n);
  attn_M<<<(n + 255) / 256, 256, 0, stream>>>(s2, red, h, lab, Mbuf, out + 4, n);
  final_k<<<1, 256, 0, stream>>>(Mbuf, Wc, bc, out);
  (void)ws_size; (void)out_size; (void)n_in;
}

// Round 3
// 226.229 us; speedup vs baseline: 1.5136x; 1.1740x over previous
//
#include <hip/hip_runtime.h>
#include <hip/hip_bf16.h>
#include <math.h>

typedef float f32x4_t __attribute__((ext_vector_type(4)));
typedef float f32x2_t __attribute__((ext_vector_type(2)));
typedef __bf16 bf16x8_t __attribute__((ext_vector_type(8)));

__device__ __forceinline__ float bf2f(unsigned int u){
  union { float f; unsigned int i; } x; x.i = u << 16; return x.f;
}
__device__ __forceinline__ unsigned short f2bf(float f){
  unsigned int x = __float_as_uint(f);
  unsigned int r = (x + 0x7fffu + ((x >> 16) & 1u)) >> 16;
  return (unsigned short)r;
}
// unpack 8 bf16 (uint4) -> 8 floats, scaled
__device__ __forceinline__ void unp8s(uint4 w, float* f, float s){
  f[0] = bf2f(w.x & 0xffffu) * s; f[1] = bf2f(w.x >> 16) * s;
  f[2] = bf2f(w.y & 0xffffu) * s; f[3] = bf2f(w.y >> 16) * s;
  f[4] = bf2f(w.z & 0xffffu) * s; f[5] = bf2f(w.z >> 16) * s;
  f[6] = bf2f(w.w & 0xffffu) * s; f[7] = bf2f(w.w >> 16) * s;
}
// unpack 4 fp8 e4m3 (one u32) -> 4 floats (HW cvt)
__device__ __forceinline__ void unpf8(unsigned int w, float* f){
  f32x2_t lo = __builtin_amdgcn_cvt_pk_f32_fp8(w, false);
  f32x2_t hi = __builtin_amdgcn_cvt_pk_f32_fp8(w, true);
  f[0] = lo[0]; f[1] = lo[1]; f[2] = hi[0]; f[3] = hi[1];
}

#define GLOAD16(gsrc, ldst) \
  __builtin_amdgcn_global_load_lds((const __attribute__((address_space(1))) unsigned int*)(gsrc), \
                                   (__attribute__((address_space(3))) unsigned int*)(ldst), 16, 0, 0)

// ---------------- K0: pack weights (Wq|Wk|Wv|Ws) -> wcatT bf16 [1024][512], biases -> bcat f32[1024]
__global__ void pack_weights(const float* __restrict__ Wq, const float* __restrict__ Wk,
                             const float* __restrict__ Wv, const float* __restrict__ Ws,
                             const float* __restrict__ bq, const float* __restrict__ bk,
                             const float* __restrict__ bv, const float* __restrict__ bs,
                             unsigned short* __restrict__ wcatT, float* __restrict__ bcat){
  int idx = blockIdx.x * 256 + threadIdx.x;
  if (idx < 1024 * 512){
    int c = idx >> 9, k = idx & 511;
    int sel = c >> 8, cc = c & 255;
    const float* W = (sel == 0) ? Wq : (sel == 1) ? Wk : (sel == 2) ? Wv : Ws;
    wcatT[idx] = f2bf(W[k * 256 + cc]);
  }
  if (idx < 1024){
    int sel = idx >> 8, cc = idx & 255;
    const float* B = (sel == 0) ? bq : (sel == 1) ? bk : (sel == 2) ? bv : bs;
    bcat[idx] = B[cc];
  }
}

// ---------------- K0b: pack Wa1^T -> bf16 [256 cols][256 k]
__global__ void pack_wa1(const float* __restrict__ Wa1, unsigned short* __restrict__ wa1T){
  int idx = blockIdx.x * 256 + threadIdx.x;  // 65536
  int c = idx >> 8, k = idx & 255;
  wa1T[idx] = f2bf(Wa1[k * 256 + c]);
}

// ---------------- K1: x fp32 -> bf16
__global__ void convert_x(const float* __restrict__ x, unsigned short* __restrict__ xbf, int n4){
  int i = blockIdx.x * 256 + threadIdx.x;
  if (i < n4){
    float4 v = reinterpret_cast<const float4*>(x)[i];
    ushort4 o;
    o.x = f2bf(v.x); o.y = f2bf(v.y); o.z = f2bf(v.z); o.w = f2bf(v.w);
    reinterpret_cast<ushort4*>(xbf)[i] = o;
  }
}

// ---------------- K3: qkvs[n][1024] = xbf[n][512] @ wcatT^T + bcat  (bf16 MFMA, 128x128 tile, gload_lds)
__global__ __launch_bounds__(256) void gemm_qkvs(const unsigned short* __restrict__ xbf,
                                                 const unsigned short* __restrict__ wcatT,
                                                 const float* __restrict__ bcat,
                                                 unsigned short* __restrict__ qkvs, int n_nodes){
  __shared__ __align__(16) unsigned short As[128 * 32];
  __shared__ __align__(16) unsigned short Bs[128 * 32];
  const int tid = threadIdx.x;
  const int lane = tid & 63, wave = tid >> 6;
  const int wm = wave >> 1, wn = wave & 1;
  const int m0 = blockIdx.y * 128, n0 = blockIdx.x * 128;
  const int lrow = lane >> 2;          // 0..15 within 16-row chunk
  const int lcol = (lane & 3) * 8;     // elem col within 32
  const int rA0 = min(m0 + wave * 16 + lrow, n_nodes - 1);
  const int rA1 = min(m0 + (wave + 4) * 16 + lrow, n_nodes - 1);
  const int rB0 = n0 + wave * 16 + lrow;
  const int rB1 = n0 + (wave + 4) * 16 + lrow;
  const int r = lane & 15, ko = (lane >> 4) * 8;
  f32x4_t acc[4][4] = {};
  for (int k0 = 0; k0 < 512; k0 += 32){
    GLOAD16(xbf   + (size_t)rA0 * 512 + k0 + lcol, &As[wave * 512]);
    GLOAD16(xbf   + (size_t)rA1 * 512 + k0 + lcol, &As[(wave + 4) * 512]);
    GLOAD16(wcatT + (size_t)rB0 * 512 + k0 + lcol, &Bs[wave * 512]);
    GLOAD16(wcatT + (size_t)rB1 * 512 + k0 + lcol, &Bs[(wave + 4) * 512]);
    __syncthreads();
    bf16x8_t a[4], b[4];
    #pragma unroll
    for (int mi = 0; mi < 4; mi++)
      a[mi] = *reinterpret_cast<const bf16x8_t*>(&As[(wm * 64 + mi * 16 + r) * 32 + ko]);
    #pragma unroll
    for (int ni = 0; ni < 4; ni++)
      b[ni] = *reinterpret_cast<const bf16x8_t*>(&Bs[(wn * 64 + ni * 16 + r) * 32 + ko]);
    #pragma unroll
    for (int mi = 0; mi < 4; mi++)
      #pragma unroll
      for (int ni = 0; ni < 4; ni++)
        acc[mi][ni] = __builtin_amdgcn_mfma_f32_16x16x32_bf16(a[mi], b[ni], acc[mi][ni], 0, 0, 0);
    __syncthreads();
  }
  const int rg = (lane >> 4) * 4;
  #pragma unroll
  for (int ni = 0; ni < 4; ni++){
    int gcol = n0 + wn * 64 + ni * 16 + r;
    float bb = bcat[gcol];
    #pragma unroll
    for (int mi = 0; mi < 4; mi++){
      #pragma unroll
      for (int j = 0; j < 4; j++){
        int grow = m0 + wm * 64 + mi * 16 + rg + j;
        if (grow < n_nodes)
          qkvs[(size_t)grow * 1024 + gcol] = f2bf(acc[mi][ni][j] + bb);
      }
    }
  }
}

// ---------------- K3b: pack K,V cols of qkvs -> fp8 e4m3 kv8[n][512]
__global__ void pack_kv8(const unsigned short* __restrict__ qkvs, unsigned char* __restrict__ kv8, int n){
  int idx = blockIdx.x * 256 + threadIdx.x;   // n*64 threads, 8 elems each
  if (idx >= n * 64) return;
  int node = idx >> 6, part = idx & 63;
  const unsigned short* src = qkvs + (size_t)node * 1024 + 256 + part * 8;
  uint4 w = *reinterpret_cast<const uint4*>(src);
  float f[8]; unp8s(w, f, 1.0f);
  int lo = 0, hi = 0;
  lo = __builtin_amdgcn_cvt_pk_fp8_f32(f[0], f[1], lo, false);
  lo = __builtin_amdgcn_cvt_pk_fp8_f32(f[2], f[3], lo, true);
  hi = __builtin_amdgcn_cvt_pk_fp8_f32(f[4], f[5], hi, false);
  hi = __builtin_amdgcn_cvt_pk_fp8_f32(f[6], f[7], hi, true);
  uint2 o; o.x = (unsigned int)lo; o.y = (unsigned int)hi;
  *reinterpret_cast<uint2*>(kv8 + (size_t)node * 512 + part * 8) = o;
}

// ---------------- K4: degree histogram
__global__ void degree_hist(const int* __restrict__ ei, int* __restrict__ deg, int ne){
  int i = blockIdx.x * 256 + threadIdx.x;
  if (i < ne) atomicAdd(&deg[ei[ne + i]], 1);
}

// ---------------- K5: exclusive scan, single block, 2-pass blocked
__global__ void scan_deg(const int* __restrict__ deg, int* __restrict__ rowstart, int n, int ne){
  __shared__ int sm[1024];
  int tid = threadIdx.x;
  int per = (n + 1023) / 1024;
  int start = tid * per;
  int sum = 0;
  for (int i = 0; i < per; i++){
    int idx = start + i;
    sum += (idx < n) ? deg[idx] : 0;
  }
  sm[tid] = sum; __syncthreads();
  for (int off = 1; off < 1024; off <<= 1){
    int t = (tid >= off) ? sm[tid - off] : 0;
    __syncthreads();
    sm[tid] += t;
    __syncthreads();
  }
  int run = sm[tid] - sum;   // exclusive prefix of this thread's chunk
  for (int i = 0; i < per; i++){
    int idx = start + i;
    if (idx < n){
      rowstart[idx] = run;
      run += deg[idx];
    }
  }
  if (tid == 0) rowstart[n] = ne;
}

// ---------------- K6: scatter edges into CSR (stores src*512 byte-offset)
__global__ void scatter_edges(const int* __restrict__ ei, const int* __restrict__ rowstart,
                              int* __restrict__ cursor, int* __restrict__ csrsrc, int ne){
  int i = blockIdx.x * 256 + threadIdx.x;
  if (i < ne){
    int d = ei[ne + i];
    int pos = atomicAdd(&cursor[d], 1);
    csrsrc[rowstart[d] + pos] = ei[i] << 9;
  }
}

// ---------------- K7: per-dst online-softmax aggregation (fp8 K/V, 16 lanes/edge, 4 nodes/wave)
__global__ __launch_bounds__(256) void edge_attn(const unsigned short* __restrict__ qkvs,
                                                 const unsigned char* __restrict__ kv8,
                                                 const int* __restrict__ rowstart,
                                                 const int* __restrict__ csrsrc,
                                                 unsigned short* __restrict__ hbf, int n_nodes){
  const int tid = threadIdx.x;
  const int lane = tid & 63, wave = tid >> 6;
  const int g = lane >> 4, t = lane & 15;
  const int node = blockIdx.x * 16 + wave * 4 + g;
  const bool active = node < n_nodes;
  const int nd = active ? node : 0;
  const float qs = 0.0625f * 1.44269504088896340736f;  // (1/sqrt(256)) * log2(e)
  float q[16];
  {
    const unsigned short* qp = qkvs + (size_t)nd * 1024 + t * 16;
    uint4 w0 = *reinterpret_cast<const uint4*>(qp);
    uint4 w1 = *reinterpret_cast<const uint4*>(qp + 8);
    unp8s(w0, q, qs); unp8s(w1, q + 8, qs);
  }
  int rs = rowstart[nd];
  int re = active ? rowstart[nd + 1] : rs;
  float m = -1e30f, den = 0.f;
  float acc[16];
  #pragma unroll
  for (int j = 0; j < 16; j++) acc[j] = 0.f;
  for (int i = rs; i < re; i++){
    int soff = csrsrc[i];
    const unsigned char* kb = kv8 + (size_t)soff + t * 16;
    uint4 kw = *reinterpret_cast<const uint4*>(kb);
    float kf[16];
    unpf8(kw.x, kf); unpf8(kw.y, kf + 4); unpf8(kw.z, kf + 8); unpf8(kw.w, kf + 12);
    float s = 0.f;
    #pragma unroll
    for (int j = 0; j < 16; j++) s = fmaf(q[j], kf[j], s);
    s += __shfl_xor(s, 1); s += __shfl_xor(s, 2);
    s += __shfl_xor(s, 4); s += __shfl_xor(s, 8);
    uint4 vw = *reinterpret_cast<const uint4*>(kb + 256);
    float vf[16];
    unpf8(vw.x, vf); unpf8(vw.y, vf + 4); unpf8(vw.z, vf + 8); unpf8(vw.w, vf + 12);
    if (s > m){                       // new max: e == 1, rescale old state
      float sc = exp2f(m - s);
      den = den * sc + 1.0f;
      #pragma unroll
      for (int j = 0; j < 16; j++) acc[j] = fmaf(acc[j], sc, vf[j]);
      m = s;
    } else {                          // no rescale
      float e = exp2f(s - m);
      den += e;
      #pragma unroll
      for (int j = 0; j < 16; j++) acc[j] = fmaf(e, vf[j], acc[j]);
    }
  }
  float inv = (den > 0.f) ? 1.f / den : 0.f;
  const unsigned short* sp = qkvs + (size_t)nd * 1024 + 768 + t * 16;
  uint4 s0 = *reinterpret_cast<const uint4*>(sp);
  uint4 s1 = *reinterpret_cast<const uint4*>(sp + 8);
  float sf[16]; unp8s(s0, sf, 1.0f); unp8s(s1, sf + 8, 1.0f);
  const float inv_sqrt2 = 0.70710678118654752f;
  unsigned int o[8];
  #pragma unroll
  for (int j = 0; j < 8; j++){
    float h0 = acc[2 * j] * inv + sf[2 * j];
    float h1 = acc[2 * j + 1] * inv + sf[2 * j + 1];
    h0 = 0.5f * h0 * (1.f + erff(h0 * inv_sqrt2));
    h1 = 0.5f * h1 * (1.f + erff(h1 * inv_sqrt2));
    o[j] = (unsigned int)f2bf(h0) | ((unsigned int)f2bf(h1) << 16);
  }
  if (active){
    uint4* dst = reinterpret_cast<uint4*>(hbf + (size_t)node * 256 + t * 16);
    dst[0] = make_uint4(o[0], o[1], o[2], o[3]);
    dst[1] = make_uint4(o[4], o[5], o[6], o[7]);
  }
}

// ---------------- K8: s2[n][2] = tanh(hbf@Wa1 + ba1)@Wa2 + ba2  (bf16 MFMA)
__global__ __launch_bounds__(256) void mlp_mfma(const unsigned short* __restrict__ hbf,
                                                const unsigned short* __restrict__ wa1T,
                                                const float* __restrict__ ba1,
                                                const float* __restrict__ Wa2,
                                                const float* __restrict__ ba2,
                                                float* __restrict__ s2, int n_nodes){
  __shared__ __align__(16) unsigned short As[64 * 72];
  __shared__ float s2s[64][2];
  const int tid = threadIdx.x;
  const int lane = tid & 63, wave = tid >> 6;
  const int m0 = blockIdx.x * 64;
  const int c0 = wave * 64;
  const int r = lane & 15, rg = (lane >> 4) * 4;
  if (tid < 128) s2s[tid >> 1][tid & 1] = 0.f;
  f32x4_t acc[4][4] = {};
  for (int k0 = 0; k0 < 256; k0 += 64){
    int arow = tid >> 2, akc = (tid & 3) * 16;
    uint4 a0v = make_uint4(0,0,0,0), a1v = make_uint4(0,0,0,0);
    if (m0 + arow < n_nodes){
      const unsigned short* src = hbf + (size_t)(m0 + arow) * 256 + k0 + akc;
      a0v = *reinterpret_cast<const uint4*>(src);
      a1v = *reinterpret_cast<const uint4*>(src + 8);
    }
    *reinterpret_cast<uint4*>(&As[arow * 72 + akc]) = a0v;
    *reinterpret_cast<uint4*>(&As[arow * 72 + akc + 8]) = a1v;
    __syncthreads();
    #pragma unroll
    for (int kk = 0; kk < 2; kk++){
      int kg = kk * 32 + (lane >> 4) * 8;
      bf16x8_t a[4], b[4];
      #pragma unroll
      for (int mi = 0; mi < 4; mi++)
        a[mi] = *reinterpret_cast<const bf16x8_t*>(&As[(mi * 16 + r) * 72 + kg]);
      #pragma unroll
      for (int ni = 0; ni < 4; ni++)
        b[ni] = *reinterpret_cast<const bf16x8_t*>(wa1T + (size_t)(c0 + ni * 16 + r) * 256 + k0 + kg);
      #pragma unroll
      for (int mi = 0; mi < 4; mi++)
        #pragma unroll
        for (int ni = 0; ni < 4; ni++)
          acc[mi][ni] = __builtin_amdgcn_mfma_f32_16x16x32_bf16(a[mi], b[ni], acc[mi][ni], 0, 0, 0);
    }
    __syncthreads();
  }
  float w20[4], w21[4], b1c[4];
  #pragma unroll
  for (int ni = 0; ni < 4; ni++){
    int col = c0 + ni * 16 + r;
    w20[ni] = Wa2[col * 2]; w21[ni] = Wa2[col * 2 + 1]; b1c[ni] = ba1[col];
  }
  #pragma unroll
  for (int mi = 0; mi < 4; mi++){
    #pragma unroll
    for (int j = 0; j < 4; j++){
      float t0 = 0.f, t1 = 0.f;
      #pragma unroll
      for (int ni = 0; ni < 4; ni++){
        float t = tanhf(acc[mi][ni][j] + b1c[ni]);
        t0 += t * w20[ni]; t1 += t * w21[ni];
      }
      t0 += __shfl_xor(t0, 1); t0 += __shfl_xor(t0, 2);
      t0 += __shfl_xor(t0, 4); t0 += __shfl_xor(t0, 8);
      t1 += __shfl_xor(t1, 1); t1 += __shfl_xor(t1, 2);
      t1 += __shfl_xor(t1, 4); t1 += __shfl_xor(t1, 8);
      if (r == 0){
        int row = mi * 16 + rg + j;
        atomicAdd(&s2s[row][0], t0);
        atomicAdd(&s2s[row][1], t1);
      }
    }
  }
  __syncthreads();
  if (tid < 128){
    int row = tid >> 1, c = tid & 1;
    int node = m0 + row;
    if (node < n_nodes) s2[node * 2 + c] = s2s[row][c] + ba2[c];
  }
}

// ---------------- K9: column max + exp-sum over n (single block)
__global__ void col_reduce(const float* __restrict__ s2, float* __restrict__ red, int n){
  __shared__ float sm[1024];
  __shared__ float mshare[2];
  int tid = threadIdx.x;
  float mx0 = -INFINITY, mx1 = -INFINITY;
  for (int i = tid; i < n; i += 1024){
    mx0 = fmaxf(mx0, s2[2 * i]);
    mx1 = fmaxf(mx1, s2[2 * i + 1]);
  }
  sm[tid] = mx0; __syncthreads();
  for (int off = 512; off > 0; off >>= 1){
    if (tid < off) sm[tid] = fmaxf(sm[tid], sm[tid + off]);
    __syncthreads();
  }
  if (tid == 0) mshare[0] = sm[0];
  __syncthreads();
  sm[tid] = mx1; __syncthreads();
  for (int off = 512; off > 0; off >>= 1){
    if (tid < off) sm[tid] = fmaxf(sm[tid], sm[tid + off]);
    __syncthreads();
  }
  if (tid == 0) mshare[1] = sm[0];
  __syncthreads();
  float m0 = mshare[0], m1 = mshare[1];
  float s0 = 0.f, s1 = 0.f;
  for (int i = tid; i < n; i += 1024){
    s0 += expf(s2[2 * i] - m0);
    s1 += expf(s2[2 * i + 1] - m1);
  }
  sm[tid] = s0; __syncthreads();
  for (int off = 512; off > 0; off >>= 1){
    if (tid < off) sm[tid] += sm[tid + off];
    __syncthreads();
  }
  float den0 = sm[0];
  __syncthreads();
  sm[tid] = s1; __syncthreads();
  for (int off = 512; off > 0; off >>= 1){
    if (tid < off) sm[tid] += sm[tid + off];
    __syncthreads();
  }
  if (tid == 0){
    red[0] = m0; red[1] = m1; red[2] = den0; red[3] = sm[0];
  }
}

// ---------------- K10: attn, A output, M partial accumulation (reads bf16 h)
__global__ __launch_bounds__(256) void attn_M(const float* __restrict__ s2, const float* __restrict__ red,
                                              const unsigned short* __restrict__ hbf, const int* __restrict__ label,
                                              float* __restrict__ Mbuf, float* __restrict__ outA, int n){
  __shared__ float a0s[256], a1s[256];
  int tid = threadIdx.x;
  int n0 = blockIdx.x * 256;
  int node = n0 + tid;
  float m0 = red[0], m1 = red[1];
  float i0 = 1.f / red[2], i1 = 1.f / red[3];
  float a0 = 0.f, a1 = 0.f;
  if (node < n){
    a0 = expf(s2[2 * node] - m0) * i0;
    a1 = expf(s2[2 * node + 1] - m1) * i1;
    outA[node] = (label[0] == 0) ? a0 : a1;
  }
  a0s[tid] = a0; a1s[tid] = a1;
  __syncthreads();
  int d = tid;
  float M0 = 0.f, M1 = 0.f;
  int cnt = min(256, n - n0);
  for (int i = 0; i < cnt; i++){
    float hv = bf2f((unsigned int)hbf[(size_t)(n0 + i) * 256 + d]);
    M0 += a0s[i] * hv;
    M1 += a1s[i] * hv;
  }
  atomicAdd(&Mbuf[d], M0);
  atomicAdd(&Mbuf[256 + d], M1);
}

// ---------------- K11: logits + Y_prob
__global__ void final_k(const float* __restrict__ Mbuf, const float* __restrict__ Wc,
                        const float* __restrict__ bc, float* __restrict__ out){
  __shared__ float sm[256];
  __shared__ float l0s;
  int tid = threadIdx.x;
  float p0 = Mbuf[tid] * Wc[tid];
  float p1 = Mbuf[256 + tid] * Wc[256 + tid];
  sm[tid] = p0; __syncthreads();
  for (int off = 128; off > 0; off >>= 1){
    if (tid < off) sm[tid] += sm[tid + off];
    __syncthreads();
  }
  if (tid == 0) l0s = sm[0];
  __syncthreads();
  sm[tid] = p1; __syncthreads();
  for (int off = 128; off > 0; off >>= 1){
    if (tid < off) sm[tid] += sm[tid + off];
    __syncthreads();
  }
  if (tid == 0){
    float l0 = l0s + bc[0];
    float l1 = sm[0] + bc[1];
    out[0] = l0; out[1] = l1;
    float mx = fmaxf(l0, l1);
    float e0 = expf(l0 - mx), e1 = expf(l1 - mx);
    float inv = 1.f / (e0 + e1);
    out[2] = e0 * inv; out[3] = e1 * inv;
  }
}

extern "C" void kernel_launch(void* const* d_in, const int* in_sizes, int n_in,
                              void* d_out, int out_size, void* d_ws, size_t ws_size,
                              hipStream_t stream) {
  const float* x   = (const float*)d_in[0];
  const int*   ei  = (const int*)d_in[1];
  const int*   lab = (const int*)d_in[2];
  const float* Wq  = (const float*)d_in[3];
  const float* bq  = (const float*)d_in[4];
  const float* Wk  = (const float*)d_in[5];
  const float* bk  = (const float*)d_in[6];
  const float* Wv  = (const float*)d_in[7];
  const float* bv  = (const float*)d_in[8];
  const float* Ws  = (const float*)d_in[9];
  const float* bs  = (const float*)d_in[10];
  const float* Wa1 = (const float*)d_in[11];
  const float* ba1 = (const float*)d_in[12];
  const float* Wa2 = (const float*)d_in[13];
  const float* ba2 = (const float*)d_in[14];
  const float* Wc  = (const float*)d_in[15];
  const float* bc  = (const float*)d_in[16];
  float* out = (float*)d_out;

  const int n  = in_sizes[0] / 512;   // 20000
  const int ne = in_sizes[1] / 2;     // 320000

  char* ws = (char*)d_ws;
  size_t off = 0;
  auto take = [&](size_t bytes){ size_t r = off; off += (bytes + 255) & ~(size_t)255; return r; };
  unsigned short* xbf    = (unsigned short*)(ws + take((size_t)n * 512 * 2));
  unsigned short* wcatT  = (unsigned short*)(ws + take((size_t)1024 * 512 * 2));
  float*          bcat   = (float*)(ws + take(1024 * 4));
  unsigned short* qkvs   = (unsigned short*)(ws + take((size_t)n * 1024 * 2));
  unsigned char*  kv8    = (unsigned char*)(ws + take((size_t)n * 512));
  unsigned short* hbf    = (unsigned short*)(ws + take((size_t)n * 256 * 2));
  unsigned short* wa1T   = (unsigned short*)(ws + take((size_t)256 * 256 * 2));
  float*          s2     = (float*)(ws + take((size_t)n * 2 * 4));
  // zero-init block: deg, cursor, Mbuf contiguous
  size_t zoff = off;
  int*            deg    = (int*)(ws + take((size_t)n * 4));
  int*            cursor = (int*)(ws + take((size_t)n * 4));
  float*          Mbuf   = (float*)(ws + take(512 * 4));
  size_t zlen = off - zoff;
  int*            rowst  = (int*)(ws + take((size_t)(n + 1) * 4));
  int*            csrsrc = (int*)(ws + take((size_t)ne * 4));
  float*          red    = (float*)(ws + take(4 * 4));

  hipMemsetAsync(ws + zoff, 0, zlen, stream);

  pack_weights<<<(1024 * 512 + 255) / 256, 256, 0, stream>>>(Wq, Wk, Wv, Ws, bq, bk, bv, bs, wcatT, bcat);
  pack_wa1<<<256, 256, 0, stream>>>(Wa1, wa1T);
  convert_x<<<(n * 512 / 4 + 255) / 256, 256, 0, stream>>>(x, xbf, n * 512 / 4);
  dim3 ggrid(8, (n + 127) / 128);
  gemm_qkvs<<<ggrid, 256, 0, stream>>>(xbf, wcatT, bcat, qkvs, n);
  pack_kv8<<<(n * 64 + 255) / 256, 256, 0, stream>>>(qkvs, kv8, n);
  degree_hist<<<(ne + 255) / 256, 256, 0, stream>>>(ei, deg, ne);
  scan_deg<<<1, 1024, 0, stream>>>(deg, rowst, n, ne);
  scatter_edges<<<(ne + 255) / 256, 256, 0, stream>>>(ei, rowst, cursor, csrsrc, ne);
  edge_attn<<<(n + 15) / 16, 256, 0, stream>>>(qkvs, kv8, rowst, csrsrc, hbf, n);
  mlp_mfma<<<(n + 63) / 64, 256, 0, stream>>>(hbf, wa1T, ba1, Wa2, ba2, s2, n);
  col_reduce<<<1, 1024, 0, stream>>>(s2, red, n);
  attn_M<<<(n + 255) / 256, 256, 0, stream>>>(s2, red, hbf, lab, Mbuf, out + 4, n);
  final_k<<<1, 256, 0, stream>>>(Mbuf, Wc, bc, out);
  (void)ws_size; (void)out_size; (void)n_in;
}

// Round 4
// 218.926 us; speedup vs baseline: 1.5641x; 1.0334x over previous
//
#include <hip/hip_runtime.h>
#include <hip/hip_bf16.h>
#include <math.h>

typedef float f32x4_t __attribute__((ext_vector_type(4)));
typedef float f32x2_t __attribute__((ext_vector_type(2)));
typedef __bf16 bf16x8_t __attribute__((ext_vector_type(8)));

__device__ __forceinline__ float bf2f(unsigned int u){
  union { float f; unsigned int i; } x; x.i = u << 16; return x.f;
}
__device__ __forceinline__ unsigned short f2bf(float f){
  unsigned int x = __float_as_uint(f);
  unsigned int r = (x + 0x7fffu + ((x >> 16) & 1u)) >> 16;
  return (unsigned short)r;
}
__device__ __forceinline__ unsigned int pk2bf(float a, float b){
  return (unsigned int)f2bf(a) | ((unsigned int)f2bf(b) << 16);
}
// unpack 8 bf16 (uint4) -> 8 floats, scaled
__device__ __forceinline__ void unp8s(uint4 w, float* f, float s){
  f[0] = bf2f(w.x & 0xffffu) * s; f[1] = bf2f(w.x >> 16) * s;
  f[2] = bf2f(w.y & 0xffffu) * s; f[3] = bf2f(w.y >> 16) * s;
  f[4] = bf2f(w.z & 0xffffu) * s; f[5] = bf2f(w.z >> 16) * s;
  f[6] = bf2f(w.w & 0xffffu) * s; f[7] = bf2f(w.w >> 16) * s;
}
// unpack 4 fp8 e4m3 (one u32) -> 4 floats (HW cvt)
__device__ __forceinline__ void unpf8(unsigned int w, float* f){
  f32x2_t lo = __builtin_amdgcn_cvt_pk_f32_fp8(w, false);
  f32x2_t hi = __builtin_amdgcn_cvt_pk_f32_fp8(w, true);
  f[0] = lo[0]; f[1] = lo[1]; f[2] = hi[0]; f[3] = hi[1];
}

#define GLOAD16(gsrc, ldst) \
  __builtin_amdgcn_global_load_lds((const __attribute__((address_space(1))) unsigned int*)(gsrc), \
                                   (__attribute__((address_space(3))) unsigned int*)(ldst), 16, 0, 0)

// ---------------- K0: pack weights (Wq|Wk|Wv|Ws) -> wcatT bf16 [1024][512], biases -> bcat f32[1024]
__global__ void pack_weights(const float* __restrict__ Wq, const float* __restrict__ Wk,
                             const float* __restrict__ Wv, const float* __restrict__ Ws,
                             const float* __restrict__ bq, const float* __restrict__ bk,
                             const float* __restrict__ bv, const float* __restrict__ bs,
                             unsigned short* __restrict__ wcatT, float* __restrict__ bcat){
  int idx = blockIdx.x * 256 + threadIdx.x;
  if (idx < 1024 * 512){
    int c = idx >> 9, k = idx & 511;
    int sel = c >> 8, cc = c & 255;
    const float* W = (sel == 0) ? Wq : (sel == 1) ? Wk : (sel == 2) ? Wv : Ws;
    wcatT[idx] = f2bf(W[k * 256 + cc]);
  }
  if (idx < 1024){
    int sel = idx >> 8, cc = idx & 255;
    const float* B = (sel == 0) ? bq : (sel == 1) ? bk : (sel == 2) ? bv : bs;
    bcat[idx] = B[cc];
  }
}

// ---------------- K0b: pack Wa1^T -> bf16 [256 cols][256 k]
__global__ void pack_wa1(const float* __restrict__ Wa1, unsigned short* __restrict__ wa1T){
  int idx = blockIdx.x * 256 + threadIdx.x;  // 65536
  int c = idx >> 8, k = idx & 255;
  wa1T[idx] = f2bf(Wa1[k * 256 + c]);
}

// ---------------- K3: fused QKVS GEMM: reads x fp32, writes q/s bf16 + k/v fp8
// 128x128 tile; XCD-swizzled 1D grid (8 n-blocks fastest within an XCD's m-range);
// swapped-operand MFMA so each lane owns 4 consecutive output cols; LDS-staged epilogue.
__global__ __launch_bounds__(256) void gemm_qkvs(const float* __restrict__ x,
                                                 const unsigned short* __restrict__ wcatT,
                                                 const float* __restrict__ bcat,
                                                 unsigned short* __restrict__ qbf,
                                                 unsigned short* __restrict__ sbf,
                                                 unsigned char* __restrict__ kv8,
                                                 int n_nodes, int mblocks){
  __shared__ __align__(16) unsigned char smem[128 * 272];   // 34KB: K-loop uses 16KB, epilogue up to 34KB
  unsigned short* As = (unsigned short*)smem;                // [128][32] bf16
  unsigned short* Bs = (unsigned short*)(smem + 8192);       // [128][32] bf16
  const int tid = threadIdx.x;
  const int lane = tid & 63, wave = tid >> 6;
  const int wm = wave >> 1, wn = wave & 1;
  // bijective XCD swizzle: all 8 n-blocks of one m-tile land on one XCD
  const int g = (blockIdx.x & 7) * mblocks + (blockIdx.x >> 3);
  const int m_blk = g >> 3, n_blk = g & 7;
  const int m0 = m_blk * 128, n0 = n_blk * 128;
  // A staging (fp32 -> bf16 in regs)
  const int arow = tid >> 1;
  const int acol = (tid & 1) * 16;
  const float* aptr = x + (size_t)min(m0 + arow, n_nodes - 1) * 512 + acol;
  unsigned short* adst = &As[arow * 32 + acol];
  // B rows for global_load_lds
  const int brow = n0 + wave * 16 + (lane >> 2);
  const int bcol = (lane & 3) * 8;
  const int r = lane & 15, ko = (lane >> 4) * 8, ng = lane >> 4;
  f32x4_t acc[4][4] = {};
  for (int k0 = 0; k0 < 512; k0 += 32){
    GLOAD16(wcatT + (size_t)brow * 512 + k0 + bcol, &Bs[wave * 512]);
    GLOAD16(wcatT + (size_t)(brow + 64) * 512 + k0 + bcol, &Bs[(wave + 4) * 512]);
    float4 f0 = *reinterpret_cast<const float4*>(aptr + k0);
    float4 f1 = *reinterpret_cast<const float4*>(aptr + k0 + 4);
    float4 f2 = *reinterpret_cast<const float4*>(aptr + k0 + 8);
    float4 f3 = *reinterpret_cast<const float4*>(aptr + k0 + 12);
    uint4 o0, o1;
    o0.x = pk2bf(f0.x, f0.y); o0.y = pk2bf(f0.z, f0.w);
    o0.z = pk2bf(f1.x, f1.y); o0.w = pk2bf(f1.z, f1.w);
    o1.x = pk2bf(f2.x, f2.y); o1.y = pk2bf(f2.z, f2.w);
    o1.z = pk2bf(f3.x, f3.y); o1.w = pk2bf(f3.z, f3.w);
    *reinterpret_cast<uint4*>(adst) = o0;
    *reinterpret_cast<uint4*>(adst + 8) = o1;
    __syncthreads();
    bf16x8_t a[4], b[4];
    #pragma unroll
    for (int mi = 0; mi < 4; mi++)
      a[mi] = *reinterpret_cast<const bf16x8_t*>(&As[(wm * 64 + mi * 16 + r) * 32 + ko]);
    #pragma unroll
    for (int ni = 0; ni < 4; ni++)
      b[ni] = *reinterpret_cast<const bf16x8_t*>(&Bs[(wn * 64 + ni * 16 + r) * 32 + ko]);
    // swapped operands: acc fragment holds row = m (lane&15), 4 consecutive n-cols per lane
    #pragma unroll
    for (int mi = 0; mi < 4; mi++)
      #pragma unroll
      for (int ni = 0; ni < 4; ni++)
        acc[mi][ni] = __builtin_amdgcn_mfma_f32_16x16x32_bf16(b[ni], a[mi], acc[mi][ni], 0, 0, 0);
    __syncthreads();
  }
  // ---- epilogue: bias add, pack, LDS stage, coalesced store ----
  const bool isQ = (n_blk < 2), isS = (n_blk >= 6);
  if (isQ || isS){
    unsigned short* St = (unsigned short*)smem;   // [128][136] bf16
    #pragma unroll
    for (int mi = 0; mi < 4; mi++){
      #pragma unroll
      for (int ni = 0; ni < 4; ni++){
        int ml = wm * 64 + mi * 16 + r;
        int nl = wn * 64 + ni * 16 + ng * 4;
        float4 bb = *reinterpret_cast<const float4*>(&bcat[n0 + nl]);
        uint2 w;
        w.x = pk2bf(acc[mi][ni][0] + bb.x, acc[mi][ni][1] + bb.y);
        w.y = pk2bf(acc[mi][ni][2] + bb.z, acc[mi][ni][3] + bb.w);
        *reinterpret_cast<uint2*>(&St[ml * 136 + nl]) = w;
      }
    }
    __syncthreads();
    unsigned short* outp = isQ ? qbf : sbf;
    const int colhalf = isQ ? n_blk : (n_blk - 6);
    #pragma unroll
    for (int it = 0; it < 8; it++){
      int t = it * 256 + tid;
      int row = t >> 4, seg = (t & 15) * 8;
      int node = m0 + row;
      if (node < n_nodes){
        uint4 v = *reinterpret_cast<const uint4*>(&St[row * 136 + seg]);
        *reinterpret_cast<uint4*>(outp + (size_t)node * 256 + colhalf * 128 + seg) = v;
      }
    }
  } else {
    unsigned char* St = smem;                     // [128][144] fp8
    #pragma unroll
    for (int mi = 0; mi < 4; mi++){
      #pragma unroll
      for (int ni = 0; ni < 4; ni++){
        int ml = wm * 64 + mi * 16 + r;
        int nl = wn * 64 + ni * 16 + ng * 4;
        float4 bb = *reinterpret_cast<const float4*>(&bcat[n0 + nl]);
        int u = 0;
        u = __builtin_amdgcn_cvt_pk_fp8_f32(acc[mi][ni][0] + bb.x, acc[mi][ni][1] + bb.y, u, false);
        u = __builtin_amdgcn_cvt_pk_fp8_f32(acc[mi][ni][2] + bb.z, acc[mi][ni][3] + bb.w, u, true);
        *reinterpret_cast<unsigned int*>(&St[ml * 144 + nl]) = (unsigned int)u;
      }
    }
    __syncthreads();
    #pragma unroll
    for (int it = 0; it < 4; it++){
      int t = it * 256 + tid;
      int row = t >> 3, seg = (t & 7) * 16;
      int node = m0 + row;
      if (node < n_nodes){
        uint4 v = *reinterpret_cast<const uint4*>(&St[row * 144 + seg]);
        *reinterpret_cast<uint4*>(kv8 + (size_t)node * 512 + (n_blk - 2) * 128 + seg) = v;
      }
    }
  }
}

// ---------------- K4: degree histogram
__global__ void degree_hist(const int* __restrict__ ei, int* __restrict__ deg, int ne){
  int i = blockIdx.x * 256 + threadIdx.x;
  if (i < ne) atomicAdd(&deg[ei[ne + i]], 1);
}

// ---------------- K5: exclusive scan, single block, 2-pass blocked
__global__ void scan_deg(const int* __restrict__ deg, int* __restrict__ rowstart, int n, int ne){
  __shared__ int sm[1024];
  int tid = threadIdx.x;
  int per = (n + 1023) / 1024;
  int start = tid * per;
  int sum = 0;
  for (int i = 0; i < per; i++){
    int idx = start + i;
    sum += (idx < n) ? deg[idx] : 0;
  }
  sm[tid] = sum; __syncthreads();
  for (int off = 1; off < 1024; off <<= 1){
    int t = (tid >= off) ? sm[tid - off] : 0;
    __syncthreads();
    sm[tid] += t;
    __syncthreads();
  }
  int run = sm[tid] - sum;
  for (int i = 0; i < per; i++){
    int idx = start + i;
    if (idx < n){
      rowstart[idx] = run;
      run += deg[idx];
    }
  }
  if (tid == 0) rowstart[n] = ne;
}

// ---------------- K6: scatter edges into CSR (stores src*512 byte-offset)
__global__ void scatter_edges(const int* __restrict__ ei, const int* __restrict__ rowstart,
                              int* __restrict__ cursor, int* __restrict__ csrsrc, int ne){
  int i = blockIdx.x * 256 + threadIdx.x;
  if (i < ne){
    int d = ei[ne + i];
    int pos = atomicAdd(&cursor[d], 1);
    csrsrc[rowstart[d] + pos] = ei[i] << 9;
  }
}

// ---------------- K7: per-dst online-softmax aggregation (fp8 K/V, 16 lanes/edge, 4 nodes/wave)
__global__ __launch_bounds__(256) void edge_attn(const unsigned short* __restrict__ qbf,
                                                 const unsigned short* __restrict__ sbf,
                                                 const unsigned char* __restrict__ kv8,
                                                 const int* __restrict__ rowstart,
                                                 const int* __restrict__ csrsrc,
                                                 unsigned short* __restrict__ hbf, int n_nodes){
  const int tid = threadIdx.x;
  const int lane = tid & 63, wave = tid >> 6;
  const int g = lane >> 4, t = lane & 15;
  const int node = blockIdx.x * 16 + wave * 4 + g;
  const bool active = node < n_nodes;
  const int nd = active ? node : 0;
  const float qs = 0.0625f * 1.44269504088896340736f;  // (1/sqrt(256)) * log2(e)
  float q[16];
  {
    const unsigned short* qp = qbf + (size_t)nd * 256 + t * 16;
    uint4 w0 = *reinterpret_cast<const uint4*>(qp);
    uint4 w1 = *reinterpret_cast<const uint4*>(qp + 8);
    unp8s(w0, q, qs); unp8s(w1, q + 8, qs);
  }
  int rs = rowstart[nd];
  int re = active ? rowstart[nd + 1] : rs;
  float m = -1e30f, den = 0.f;
  float acc[16];
  #pragma unroll
  for (int j = 0; j < 16; j++) acc[j] = 0.f;
  for (int i = rs; i < re; i++){
    int soff = csrsrc[i];
    const unsigned char* kb = kv8 + (size_t)soff + t * 16;
    uint4 kw = *reinterpret_cast<const uint4*>(kb);
    float kf[16];
    unpf8(kw.x, kf); unpf8(kw.y, kf + 4); unpf8(kw.z, kf + 8); unpf8(kw.w, kf + 12);
    float s = 0.f;
    #pragma unroll
    for (int j = 0; j < 16; j++) s = fmaf(q[j], kf[j], s);
    s += __shfl_xor(s, 1); s += __shfl_xor(s, 2);
    s += __shfl_xor(s, 4); s += __shfl_xor(s, 8);
    uint4 vw = *reinterpret_cast<const uint4*>(kb + 256);
    float vf[16];
    unpf8(vw.x, vf); unpf8(vw.y, vf + 4); unpf8(vw.z, vf + 8); unpf8(vw.w, vf + 12);
    if (s > m){
      float sc = exp2f(m - s);
      den = den * sc + 1.0f;
      #pragma unroll
      for (int j = 0; j < 16; j++) acc[j] = fmaf(acc[j], sc, vf[j]);
      m = s;
    } else {
      float e = exp2f(s - m);
      den += e;
      #pragma unroll
      for (int j = 0; j < 16; j++) acc[j] = fmaf(e, vf[j], acc[j]);
    }
  }
  float inv = (den > 0.f) ? 1.f / den : 0.f;
  const unsigned short* sp = sbf + (size_t)nd * 256 + t * 16;
  uint4 s0 = *reinterpret_cast<const uint4*>(sp);
  uint4 s1 = *reinterpret_cast<const uint4*>(sp + 8);
  float sf[16]; unp8s(s0, sf, 1.0f); unp8s(s1, sf + 8, 1.0f);
  const float inv_sqrt2 = 0.70710678118654752f;
  unsigned int o[8];
  #pragma unroll
  for (int j = 0; j < 8; j++){
    float h0 = acc[2 * j] * inv + sf[2 * j];
    float h1 = acc[2 * j + 1] * inv + sf[2 * j + 1];
    h0 = 0.5f * h0 * (1.f + erff(h0 * inv_sqrt2));
    h1 = 0.5f * h1 * (1.f + erff(h1 * inv_sqrt2));
    o[j] = (unsigned int)f2bf(h0) | ((unsigned int)f2bf(h1) << 16);
  }
  if (active){
    uint4* dst = reinterpret_cast<uint4*>(hbf + (size_t)node * 256 + t * 16);
    dst[0] = make_uint4(o[0], o[1], o[2], o[3]);
    dst[1] = make_uint4(o[4], o[5], o[6], o[7]);
  }
}

// ---------------- K8: s2[n][2] = tanh(hbf@Wa1 + ba1)@Wa2 + ba2  (bf16 MFMA)
__global__ __launch_bounds__(256) void mlp_mfma(const unsigned short* __restrict__ hbf,
                                                const unsigned short* __restrict__ wa1T,
                                                const float* __restrict__ ba1,
                                                const float* __restrict__ Wa2,
                                                const float* __restrict__ ba2,
                                                float* __restrict__ s2, int n_nodes){
  __shared__ __align__(16) unsigned short As[64 * 72];
  __shared__ float s2s[64][2];
  const int tid = threadIdx.x;
  const int lane = tid & 63, wave = tid >> 6;
  const int m0 = blockIdx.x * 64;
  const int c0 = wave * 64;
  const int r = lane & 15, rg = (lane >> 4) * 4;
  if (tid < 128) s2s[tid >> 1][tid & 1] = 0.f;
  f32x4_t acc[4][4] = {};
  for (int k0 = 0; k0 < 256; k0 += 64){
    int arow = tid >> 2, akc = (tid & 3) * 16;
    uint4 a0v = make_uint4(0,0,0,0), a1v = make_uint4(0,0,0,0);
    if (m0 + arow < n_nodes){
      const unsigned short* src = hbf + (size_t)(m0 + arow) * 256 + k0 + akc;
      a0v = *reinterpret_cast<const uint4*>(src);
      a1v = *reinterpret_cast<const uint4*>(src + 8);
    }
    *reinterpret_cast<uint4*>(&As[arow * 72 + akc]) = a0v;
    *reinterpret_cast<uint4*>(&As[arow * 72 + akc + 8]) = a1v;
    __syncthreads();
    #pragma unroll
    for (int kk = 0; kk < 2; kk++){
      int kg = kk * 32 + (lane >> 4) * 8;
      bf16x8_t a[4], b[4];
      #pragma unroll
      for (int mi = 0; mi < 4; mi++)
        a[mi] = *reinterpret_cast<const bf16x8_t*>(&As[(mi * 16 + r) * 72 + kg]);
      #pragma unroll
      for (int ni = 0; ni < 4; ni++)
        b[ni] = *reinterpret_cast<const bf16x8_t*>(wa1T + (size_t)(c0 + ni * 16 + r) * 256 + k0 + kg);
      #pragma unroll
      for (int mi = 0; mi < 4; mi++)
        #pragma unroll
        for (int ni = 0; ni < 4; ni++)
          acc[mi][ni] = __builtin_amdgcn_mfma_f32_16x16x32_bf16(a[mi], b[ni], acc[mi][ni], 0, 0, 0);
    }
    __syncthreads();
  }
  float w20[4], w21[4], b1c[4];
  #pragma unroll
  for (int ni = 0; ni < 4; ni++){
    int col = c0 + ni * 16 + r;
    w20[ni] = Wa2[col * 2]; w21[ni] = Wa2[col * 2 + 1]; b1c[ni] = ba1[col];
  }
  #pragma unroll
  for (int mi = 0; mi < 4; mi++){
    #pragma unroll
    for (int j = 0; j < 4; j++){
      float t0 = 0.f, t1 = 0.f;
      #pragma unroll
      for (int ni = 0; ni < 4; ni++){
        float t = tanhf(acc[mi][ni][j] + b1c[ni]);
        t0 += t * w20[ni]; t1 += t * w21[ni];
      }
      t0 += __shfl_xor(t0, 1); t0 += __shfl_xor(t0, 2);
      t0 += __shfl_xor(t0, 4); t0 += __shfl_xor(t0, 8);
      t1 += __shfl_xor(t1, 1); t1 += __shfl_xor(t1, 2);
      t1 += __shfl_xor(t1, 4); t1 += __shfl_xor(t1, 8);
      if (r == 0){
        int row = mi * 16 + rg + j;
        atomicAdd(&s2s[row][0], t0);
        atomicAdd(&s2s[row][1], t1);
      }
    }
  }
  __syncthreads();
  if (tid < 128){
    int row = tid >> 1, c = tid & 1;
    int node = m0 + row;
    if (node < n_nodes) s2[node * 2 + c] = s2s[row][c] + ba2[c];
  }
}

// ---------------- K9: column max + exp-sum over n (single block)
__global__ void col_reduce(const float* __restrict__ s2, float* __restrict__ red, int n){
  __shared__ float sm[1024];
  __shared__ float mshare[2];
  int tid = threadIdx.x;
  float mx0 = -INFINITY, mx1 = -INFINITY;
  for (int i = tid; i < n; i += 1024){
    mx0 = fmaxf(mx0, s2[2 * i]);
    mx1 = fmaxf(mx1, s2[2 * i + 1]);
  }
  sm[tid] = mx0; __syncthreads();
  for (int off = 512; off > 0; off >>= 1){
    if (tid < off) sm[tid] = fmaxf(sm[tid], sm[tid + off]);
    __syncthreads();
  }
  if (tid == 0) mshare[0] = sm[0];
  __syncthreads();
  sm[tid] = mx1; __syncthreads();
  for (int off = 512; off > 0; off >>= 1){
    if (tid < off) sm[tid] = fmaxf(sm[tid], sm[tid + off]);
    __syncthreads();
  }
  if (tid == 0) mshare[1] = sm[0];
  __syncthreads();
  float m0 = mshare[0], m1 = mshare[1];
  float s0 = 0.f, s1 = 0.f;
  for (int i = tid; i < n; i += 1024){
    s0 += expf(s2[2 * i] - m0);
    s1 += expf(s2[2 * i + 1] - m1);
  }
  sm[tid] = s0; __syncthreads();
  for (int off = 512; off > 0; off >>= 1){
    if (tid < off) sm[tid] += sm[tid + off];
    __syncthreads();
  }
  float den0 = sm[0];
  __syncthreads();
  sm[tid] = s1; __syncthreads();
  for (int off = 512; off > 0; off >>= 1){
    if (tid < off) sm[tid] += sm[tid + off];
    __syncthreads();
  }
  if (tid == 0){
    red[0] = m0; red[1] = m1; red[2] = den0; red[3] = sm[0];
  }
}

// ---------------- K10: attn, A output, M partial accumulation (reads bf16 h)
__global__ __launch_bounds__(256) void attn_M(const float* __restrict__ s2, const float* __restrict__ red,
                                              const unsigned short* __restrict__ hbf, const int* __restrict__ label,
                                              float* __restrict__ Mbuf, float* __restrict__ outA, int n){
  __shared__ float a0s[256], a1s[256];
  int tid = threadIdx.x;
  int n0 = blockIdx.x * 256;
  int node = n0 + tid;
  float m0 = red[0], m1 = red[1];
  float i0 = 1.f / red[2], i1 = 1.f / red[3];
  float a0 = 0.f, a1 = 0.f;
  if (node < n){
    a0 = expf(s2[2 * node] - m0) * i0;
    a1 = expf(s2[2 * node + 1] - m1) * i1;
    outA[node] = (label[0] == 0) ? a0 : a1;
  }
  a0s[tid] = a0; a1s[tid] = a1;
  __syncthreads();
  int d = tid;
  float M0 = 0.f, M1 = 0.f;
  int cnt = min(256, n - n0);
  for (int i = 0; i < cnt; i++){
    float hv = bf2f((unsigned int)hbf[(size_t)(n0 + i) * 256 + d]);
    M0 += a0s[i] * hv;
    M1 += a1s[i] * hv;
  }
  atomicAdd(&Mbuf[d], M0);
  atomicAdd(&Mbuf[256 + d], M1);
}

// ---------------- K11: logits + Y_prob
__global__ void final_k(const float* __restrict__ Mbuf, const float* __restrict__ Wc,
                        const float* __restrict__ bc, float* __restrict__ out){
  __shared__ float sm[256];
  __shared__ float l0s;
  int tid = threadIdx.x;
  float p0 = Mbuf[tid] * Wc[tid];
  float p1 = Mbuf[256 + tid] * Wc[256 + tid];
  sm[tid] = p0; __syncthreads();
  for (int off = 128; off > 0; off >>= 1){
    if (tid < off) sm[tid] += sm[tid + off];
    __syncthreads();
  }
  if (tid == 0) l0s = sm[0];
  __syncthreads();
  sm[tid] = p1; __syncthreads();
  for (int off = 128; off > 0; off >>= 1){
    if (tid < off) sm[tid] += sm[tid + off];
    __syncthreads();
  }
  if (tid == 0){
    float l0 = l0s + bc[0];
    float l1 = sm[0] + bc[1];
    out[0] = l0; out[1] = l1;
    float mx = fmaxf(l0, l1);
    float e0 = expf(l0 - mx), e1 = expf(l1 - mx);
    float inv = 1.f / (e0 + e1);
    out[2] = e0 * inv; out[3] = e1 * inv;
  }
}

extern "C" void kernel_launch(void* const* d_in, const int* in_sizes, int n_in,
                              void* d_out, int out_size, void* d_ws, size_t ws_size,
                              hipStream_t stream) {
  const float* x   = (const float*)d_in[0];
  const int*   ei  = (const int*)d_in[1];
  const int*   lab = (const int*)d_in[2];
  const float* Wq  = (const float*)d_in[3];
  const float* bq  = (const float*)d_in[4];
  const float* Wk  = (const float*)d_in[5];
  const float* bk  = (const float*)d_in[6];
  const float* Wv  = (const float*)d_in[7];
  const float* bv  = (const float*)d_in[8];
  const float* Ws  = (const float*)d_in[9];
  const float* bs  = (const float*)d_in[10];
  const float* Wa1 = (const float*)d_in[11];
  const float* ba1 = (const float*)d_in[12];
  const float* Wa2 = (const float*)d_in[13];
  const float* ba2 = (const float*)d_in[14];
  const float* Wc  = (const float*)d_in[15];
  const float* bc  = (const float*)d_in[16];
  float* out = (float*)d_out;

  const int n  = in_sizes[0] / 512;   // 20000
  const int ne = in_sizes[1] / 2;     // 320000

  char* ws = (char*)d_ws;
  size_t off = 0;
  auto take = [&](size_t bytes){ size_t r = off; off += (bytes + 255) & ~(size_t)255; return r; };
  unsigned short* wcatT  = (unsigned short*)(ws + take((size_t)1024 * 512 * 2));
  float*          bcat   = (float*)(ws + take(1024 * 4));
  unsigned short* qbf    = (unsigned short*)(ws + take((size_t)n * 256 * 2));
  unsigned short* sbf    = (unsigned short*)(ws + take((size_t)n * 256 * 2));
  unsigned char*  kv8    = (unsigned char*)(ws + take((size_t)n * 512));
  unsigned short* hbf    = (unsigned short*)(ws + take((size_t)n * 256 * 2));
  unsigned short* wa1T   = (unsigned short*)(ws + take((size_t)256 * 256 * 2));
  float*          s2     = (float*)(ws + take((size_t)n * 2 * 4));
  size_t zoff = off;
  int*            deg    = (int*)(ws + take((size_t)n * 4));
  int*            cursor = (int*)(ws + take((size_t)n * 4));
  float*          Mbuf   = (float*)(ws + take(512 * 4));
  size_t zlen = off - zoff;
  int*            rowst  = (int*)(ws + take((size_t)(n + 1) * 4));
  int*            csrsrc = (int*)(ws + take((size_t)ne * 4));
  float*          red    = (float*)(ws + take(4 * 4));

  hipMemsetAsync(ws + zoff, 0, zlen, stream);

  pack_weights<<<(1024 * 512 + 255) / 256, 256, 0, stream>>>(Wq, Wk, Wv, Ws, bq, bk, bv, bs, wcatT, bcat);
  pack_wa1<<<256, 256, 0, stream>>>(Wa1, wa1T);
  const int mblocks = (n + 127) / 128;
  gemm_qkvs<<<8 * mblocks, 256, 0, stream>>>(x, wcatT, bcat, qbf, sbf, kv8, n, mblocks);
  degree_hist<<<(ne + 255) / 256, 256, 0, stream>>>(ei, deg, ne);
  scan_deg<<<1, 1024, 0, stream>>>(deg, rowst, n, ne);
  scatter_edges<<<(ne + 255) / 256, 256, 0, stream>>>(ei, rowst, cursor, csrsrc, ne);
  edge_attn<<<(n + 15) / 16, 256, 0, stream>>>(qbf, sbf, kv8, rowst, csrsrc, hbf, n);
  mlp_mfma<<<(n + 63) / 64, 256, 0, stream>>>(hbf, wa1T, ba1, Wa2, ba2, s2, n);
  col_reduce<<<1, 1024, 0, stream>>>(s2, red, n);
  attn_M<<<(n + 255) / 256, 256, 0, stream>>>(s2, red, hbf, lab, Mbuf, out + 4, n);
  final_k<<<1, 256, 0, stream>>>(Mbuf, Wc, bc, out);
  (void)ws_size; (void)out_size; (void)n_in;
}